// Round 8
// baseline (8975.043 us; speedup 1.0000x reference)
//
#include <hip/hip_runtime.h>
#include <cstdint>
#include <cstddef>

#define L_SEQ   4096
#define BATCH   4
#define DIMM    768
#define D_INNER 1536
#define NHEADS  24
#define HEADDIM 64
#define D_STATE 16
#define CONVD   1568
#define D_IPROJ 3128
#define ZXP     3200     // padded zx row stride (6400B = 64B-aligned rows)
#define SEGLEN  64
#define NSEG    (L_SEQ / SEGLEN)   // 64

typedef _Float16 f16x8 __attribute__((ext_vector_type(8)));
typedef _Float16 f16x4 __attribute__((ext_vector_type(4)));
typedef float    f32x4 __attribute__((ext_vector_type(4)));

// ---------------------------------------------------------------------------
// f16 MFMA GEMM: C[m,n] = sum_k A[m*lda+k]*W[n*K+k] (+bias). 128x128x64 tile,
// 4 waves (2x2), 16x16x32 MFMA, XOR-swizzled LDS, XCD-band block swizzle.
// Epilogue: LDS transpose -> 64B-aligned full-line stores.
// OM: 0 = f16 out (+ col<N guard), 2 = f16 out + f32 bias,
//     3 = f32 out + bias + sigmoid(q>0) + type-mask (head fusion; N=512)
// ---------------------------------------------------------------------------
template <int OM>
__global__ __launch_bounds__(256, 2) void gemm_mfma(
    const _Float16* __restrict__ A, int lda,
    const _Float16* __restrict__ W,
    const float* __restrict__ bias,
    void* __restrict__ Cv, long ldc, long extra,
    int M, int N, int K,
    const int* __restrict__ tidsp, int thead)
{
  __shared__ __align__(16) char smem[33792];
  _Float16* As = (_Float16*)smem;              // [128][64] halfwords, swizzled
  _Float16* Ws = (_Float16*)(smem + 16384);
  const int tid = threadIdx.x;
  const int lane = tid & 63, wid = tid >> 6;
  const int wr = wid >> 1, wc = wid & 1;

  // ---- XCD-band block swizzle ----
  const int nbx = gridDim.x, nby = gridDim.y;
  const int flat = blockIdx.y * nbx + blockIdx.x;
  const int xcd = flat & 7;
  const int idx = flat >> 3;
  const int rpx = nby >> 3;             // row-tiles per XCD
  const int rl = idx % rpx;
  const int ct = idx / rpx;
  const long m0 = (long)(xcd * rpx + rl) * 128;
  const int n0 = ct * 128;

  uint4 areg[4], breg[4];

  auto loadA = [&](int k0) {
#pragma unroll
    for (int p = 0; p < 4; ++p) {
      int id = p * 256 + tid;
      int row = id >> 3, kc = id & 7;
      areg[p] = *(const uint4*)(A + (m0 + row) * (long)lda + k0 + kc * 8);
    }
  };
  auto loadB = [&](int k0) {
#pragma unroll
    for (int p = 0; p < 4; ++p) {
      int id = p * 256 + tid;
      int row = id >> 3, kc = id & 7;
      int n = n0 + row;
      uint4 z; z.x = z.y = z.z = z.w = 0u;
      breg[p] = (n < N) ? *(const uint4*)(W + (long)n * K + k0 + kc * 8) : z;
    }
  };
  auto stage = [&]() {
#pragma unroll
    for (int p = 0; p < 4; ++p) {
      int id = p * 256 + tid;
      int row = id >> 3, kc = id & 7;
      int sc = ((kc ^ (row & 7)) << 3);
      *(uint4*)&As[row * 64 + sc] = areg[p];
      *(uint4*)&Ws[row * 64 + sc] = breg[p];
    }
  };

  f32x4 acc[4][4] = {};
  loadA(0); loadB(0);
  const int la = lane & 15, lg = lane >> 4;

  for (int k0 = 0;;) {
    __syncthreads();
    stage();
    __syncthreads();
    int kn = k0 + 64;
    if (kn < K) { loadA(kn); loadB(kn); }
#pragma unroll
    for (int ks = 0; ks < 2; ++ks) {
      const int cc = ks * 4 + lg;
      f16x8 af[4], bfr[4];
#pragma unroll
      for (int i = 0; i < 4; ++i) {
        int ra = wr * 64 + i * 16 + la;
        int rb = wc * 64 + i * 16 + la;
        af[i]  = *(const f16x8*)&As[ra * 64 + ((cc ^ (ra & 7)) << 3)];
        bfr[i] = *(const f16x8*)&Ws[rb * 64 + ((cc ^ (rb & 7)) << 3)];
      }
#pragma unroll
      for (int i = 0; i < 4; ++i)
#pragma unroll
        for (int j = 0; j < 4; ++j)
          acc[i][j] = __builtin_amdgcn_mfma_f32_16x16x32_f16(af[i], bfr[j], acc[i][j], 0, 0, 0);
    }
    k0 = kn;
    if (k0 >= K) break;
  }

  // ---- epilogue via LDS transpose (2 phases of 64 rows) ----
  float* epi = (float*)smem;                    // [64][132]
#pragma unroll
  for (int ph = 0; ph < 2; ++ph) {
    __syncthreads();
    if (wr == ph) {
#pragma unroll
      for (int i = 0; i < 4; ++i)
#pragma unroll
        for (int j = 0; j < 4; ++j)
#pragma unroll
          for (int r = 0; r < 4; ++r)
            epi[(i * 16 + lg * 4 + r) * 132 + wc * 64 + j * 16 + la] = acc[i][j][r];
    }
    __syncthreads();
    if (OM == 3) {
      const int q = n0 >> 7;
      const int rr = tid >> 5;        // 0..7
      const int ch = tid & 31;        // 16B chunk within row
#pragma unroll
      for (int ps = 0; ps < 8; ++ps) {
        int lrow = ps * 8 + rr;
        long gr = m0 + ph * 64 + lrow;
        float keep = (tidsp[gr] == thead) ? 1.f : 0.f;
        float4 v = *(float4*)&epi[lrow * 132 + ch * 4];
        float o[4] = {v.x, v.y, v.z, v.w};
#pragma unroll
        for (int e = 0; e < 4; ++e) {
          float vv = o[e] + bias[n0 + ch * 4 + e];
          if (q != 0) vv = 1.f / (1.f + expf(-vv));
          o[e] = vv * keep;
        }
        *(float4*)((float*)Cv + (long)q * extra + gr * 128 + ch * 4) =
            make_float4(o[0], o[1], o[2], o[3]);
      }
    } else {
      const int rr = tid >> 4;        // 0..15
      const int ch = tid & 15;        // 16B (8-f16) chunk
      const int col = n0 + ch * 8;
      float b[8] = {0.f, 0.f, 0.f, 0.f, 0.f, 0.f, 0.f, 0.f};
      if (OM == 2 && col < N) {
#pragma unroll
        for (int e = 0; e < 8; ++e) b[e] = bias[col + e];
      }
#pragma unroll
      for (int ps = 0; ps < 4; ++ps) {
        int lrow = ps * 16 + rr;
        long gr = m0 + ph * 64 + lrow;
        if (col < N) {
          float4 v0 = *(float4*)&epi[lrow * 132 + ch * 8];
          float4 v1 = *(float4*)&epi[lrow * 132 + ch * 8 + 4];
          f16x8 o = {(_Float16)(v0.x + b[0]), (_Float16)(v0.y + b[1]),
                     (_Float16)(v0.z + b[2]), (_Float16)(v0.w + b[3]),
                     (_Float16)(v1.x + b[4]), (_Float16)(v1.y + b[5]),
                     (_Float16)(v1.z + b[6]), (_Float16)(v1.w + b[7])};
          *(f16x8*)((_Float16*)Cv + gr * ldc + col) = o;
        }
      }
    }
  }
}

// ---------------------------------------------------------------------------
__global__ __launch_bounds__(256) void cvt_kernel(
    const float* __restrict__ src, _Float16* __restrict__ dst, long n4)
{
  long i = (long)blockIdx.x * 256 + threadIdx.x;
  long stride = (long)gridDim.x * 256;
  for (; i < n4; i += stride) {
    float4 v = *(const float4*)(src + i * 4);
    f16x4 o = { (_Float16)v.x, (_Float16)v.y, (_Float16)v.z, (_Float16)v.w };
    *(f16x4*)(dst + i * 4) = o;
  }
}

// how[t] -> packed [512][768] f16 in output order; hob -> hob_p[1024] (both t).
__global__ __launch_bounds__(256) void pack_head_t(
    const float* __restrict__ how, const float* __restrict__ hob,
    _Float16* __restrict__ howb, float* __restrict__ hobp, int t)
{
  const int wmap[4] = {0, 3, 1, 2};
  int idx = blockIdx.x * 256 + threadIdx.x;
  if (idx < 512 * 768) {
    int q = idx / (128 * 768);
    int rem2 = idx - q * 128 * 768;
    howb[idx] = (_Float16)how[((size_t)(t * 4 + wmap[q])) * 128 * 768 + rem2];
  }
  if (idx < 1024) {
    int tt = idx >> 9, rem = idx & 511;
    int q = rem >> 7, pp = rem & 127;
    hobp[idx] = hob[(tt * 4 + wmap[q]) * 128 + pp];
  }
}

// ---------------------------------------------------------------------------
__global__ __launch_bounds__(256) void dt_kernel(
    const _Float16* __restrict__ zx, const float* __restrict__ dtb,
    const float* __restrict__ alog, float* __restrict__ dtp,
    float* __restrict__ dap, int total)
{
  int idx = blockIdx.x * 256 + threadIdx.x;
  if (idx >= total) return;
  int bl = idx / NHEADS, hh = idx - bl * NHEADS;
  float raw = (float)zx[(size_t)bl * ZXP + (D_INNER + CONVD) + hh] + dtb[hh];
  float sp = (raw > 20.f) ? raw : log1pf(expf(raw));
  dtp[idx] = sp;
  dap[idx] = expf(-expf(alog[hh]) * sp);
}

__global__ __launch_bounds__(256) void conv_kernel(
    const _Float16* __restrict__ zx, const float* __restrict__ cw,
    const float* __restrict__ cb, float* __restrict__ xbc)
{
  int idx = blockIdx.x * 256 + threadIdx.x;
  int bl = idx / CONVD;        // 0..4095 (single batch per chunk)
  int c = idx - bl * CONVD;
  float acc = cb[c];
#pragma unroll
  for (int k = 0; k < 4; ++k) {
    int ls = bl - 3 + k;
    if (ls >= 0)
      acc = fmaf(cw[c * 4 + k],
                 (float)zx[(size_t)ls * ZXP + D_INNER + c], acc);
  }
  xbc[(size_t)bl * CONVD + c] = acc / (1.f + expf(-acc));
}

// ---------------------------------------------------------------------------
// Scan pass A: per (h,seg) local scan (h0=0), single batch per chunk.
// ---------------------------------------------------------------------------
__global__ __launch_bounds__(64) void scanA_kernel(
    float* __restrict__ xbc, const float* __restrict__ dtp,
    const float* __restrict__ dap, const float* __restrict__ Dv,
    float* __restrict__ Hseg, float* __restrict__ cumq)
{
  __shared__ float sbc[SEGLEN][32];
  __shared__ float sdt[SEGLEN], sda[SEGLEN];
  const int lane = threadIdx.x;
  const int seg = blockIdx.x & (NSEG - 1);
  const int h = blockIdx.x >> 6;       // bh with b=0
  const float Dh = Dv[h];
  const int bl0 = seg * SEGLEN;

  for (int i = lane; i < SEGLEN * 8; i += 64) {
    int t = i >> 3, q = (i & 7) << 2;
    *(float4*)&sbc[t][q] = *(const float4*)&xbc[(size_t)(bl0 + t) * CONVD + D_INNER + q];
  }
  sdt[lane] = dtp[(size_t)(bl0 + lane) * NHEADS + h];
  float myda = dap[(size_t)(bl0 + lane) * NHEADS + h];
  sda[lane] = myda;
  __syncthreads();

  float pp = myda;
#pragma unroll
  for (int off = 1; off < 64; off <<= 1) {
    float tv = __shfl_up(pp, off, 64);
    if (lane >= off) pp *= tv;
  }
  cumq[(size_t)h * L_SEQ + seg * SEGLEN + lane] = pp;

  float hs[16];
#pragma unroll
  for (int n = 0; n < 16; ++n) hs[n] = 0.f;

  size_t xaddr = (size_t)bl0 * CONVD + h * HEADDIM + lane;
  float xv = xbc[xaddr];
  for (int t = 0; t < SEGLEN; ++t) {
    float xn = (t < SEGLEN - 1) ? xbc[xaddr + CONVD] : 0.f;
    float dav = sda[t];
    float coef = sdt[t] * xv;
    float y0 = 0.f, y1 = 0.f, y2 = 0.f, y3 = 0.f;
#pragma unroll
    for (int n = 0; n < 16; ++n) {
      float hv = fmaf(hs[n], dav, coef * sbc[t][n]);
      hs[n] = hv;
      float cvv = sbc[t][16 + n];
      if ((n & 3) == 0)      y0 = fmaf(hv, cvv, y0);
      else if ((n & 3) == 1) y1 = fmaf(hv, cvv, y1);
      else if ((n & 3) == 2) y2 = fmaf(hv, cvv, y2);
      else                   y3 = fmaf(hv, cvv, y3);
    }
    xbc[xaddr] = fmaf(Dh, xv, (y0 + y1) + (y2 + y3));
    xv = xn;
    xaddr += CONVD;
  }

  float* Hst = Hseg + ((size_t)h * NSEG + seg) * 1024 + lane * 16;
#pragma unroll
  for (int n = 0; n < 16; n += 4)
    *(float4*)&Hst[n] = make_float4(hs[n], hs[n + 1], hs[n + 2], hs[n + 3]);
}

// Pass B: per h combine across segments; Hseg slot becomes ENTRY state.
__global__ __launch_bounds__(64) void scanB_kernel(
    float* __restrict__ Hseg, const float* __restrict__ cumq)
{
  const int lane = threadIdx.x;
  const int h = blockIdx.x;
  float hin[16];
#pragma unroll
  for (int n = 0; n < 16; ++n) hin[n] = 0.f;
  for (int s = 0; s < NSEG; ++s) {
    float* slot = Hseg + ((size_t)h * NSEG + s) * 1024 + lane * 16;
    float P = cumq[(size_t)h * L_SEQ + s * SEGLEN + (SEGLEN - 1)];
    float hl[16];
#pragma unroll
    for (int n = 0; n < 16; n += 4) {
      float4 v = *(float4*)(slot + n);
      hl[n] = v.x; hl[n + 1] = v.y; hl[n + 2] = v.z; hl[n + 3] = v.w;
    }
#pragma unroll
    for (int n = 0; n < 16; n += 4)
      *(float4*)(slot + n) = make_float4(hin[n], hin[n + 1], hin[n + 2], hin[n + 3]);
#pragma unroll
    for (int n = 0; n < 16; ++n) hin[n] = fmaf(P, hin[n], hl[n]);
  }
}

// Pass C: y += cumprod * (C . h_entry)
__global__ __launch_bounds__(64) void scanC_kernel(
    float* __restrict__ xbc, const float* __restrict__ Hseg,
    const float* __restrict__ cumq)
{
  const int seg = blockIdx.x & (NSEG - 1);
  if (seg == 0) return;
  __shared__ float sc[SEGLEN][16];
  __shared__ float scq[SEGLEN];
  const int lane = threadIdx.x;
  const int h = blockIdx.x >> 6;
  const int bl0 = seg * SEGLEN;
  const float* slot = Hseg + ((size_t)h * NSEG + seg) * 1024 + lane * 16;
  float hin[16];
#pragma unroll
  for (int n = 0; n < 16; n += 4) {
    float4 v = *(const float4*)(slot + n);
    hin[n] = v.x; hin[n + 1] = v.y; hin[n + 2] = v.z; hin[n + 3] = v.w;
  }
  for (int i = lane; i < SEGLEN * 4; i += 64) {
    int t = i >> 2, q = (i & 3) << 2;
    *(float4*)&sc[t][q] =
        *(const float4*)&xbc[(size_t)(bl0 + t) * CONVD + D_INNER + D_STATE + q];
  }
  scq[lane] = cumq[(size_t)h * L_SEQ + seg * SEGLEN + lane];
  __syncthreads();
  for (int t = 0; t < SEGLEN; ++t) {
    float dot = 0.f;
#pragma unroll
    for (int n = 0; n < 16; ++n) dot = fmaf(hin[n], sc[t][n], dot);
    size_t ad = (size_t)(bl0 + t) * CONVD + h * HEADDIM + lane;
    xbc[ad] = fmaf(scq[t], dot, xbc[ad]);
  }
}

// ---------------------------------------------------------------------------
// y *= silu(z); RMS-norm over 1536; * norm_w; f16 result written back into
// zx cols 0..1535 of the same row (read-all-then-write, same block => safe).
// ---------------------------------------------------------------------------
__global__ __launch_bounds__(256) void norm_kernel(
    const float* __restrict__ y, _Float16* __restrict__ zx,
    const float* __restrict__ nw)
{
  const int row = blockIdx.x;
  const int tid = threadIdx.x;
  const float* yr = y + (size_t)row * CONVD;
  _Float16* zr = zx + (size_t)row * ZXP;
  float v[6];
  float ss = 0.f;
#pragma unroll
  for (int jj = 0; jj < 6; ++jj) {
    int c = jj * 256 + tid;
    float yv = yr[c];
    float zv = (float)zr[c];
    float sz = zv / (1.f + expf(-zv));
    float val = yv * sz;
    v[jj] = val;
    ss = fmaf(val, val, ss);
  }
#pragma unroll
  for (int off = 32; off > 0; off >>= 1) ss += __shfl_xor(ss, off, 64);
  __shared__ float red[4];
  if ((tid & 63) == 0) red[tid >> 6] = ss;
  __syncthreads();
  float tot = red[0] + red[1] + red[2] + red[3];
  float rs = rsqrtf(tot * (1.f / 1536.f) + 1e-5f);
#pragma unroll
  for (int jj = 0; jj < 6; ++jj) {
    int c = jj * 256 + tid;
    zr[c] = (_Float16)(v[jj] * rs * nw[c]);
  }
}

// ---------------------------------------------------------------------------
extern "C" void kernel_launch(void* const* d_in, const int* in_sizes, int n_in,
                              void* d_out, int out_size, void* d_ws, size_t ws_size,
                              hipStream_t stream)
{
  const float* x_in = (const float*)d_in[0];
  const int*   tids = (const int*)d_in[1];
  const float* ipw  = (const float*)d_in[2];
  const float* cw   = (const float*)d_in[3];
  const float* cb   = (const float*)d_in[4];
  const float* dtb  = (const float*)d_in[5];
  const float* alog = (const float*)d_in[6];
  const float* Dv   = (const float*)d_in[7];
  const float* nw   = (const float*)d_in[8];
  const float* opw  = (const float*)d_in[9];
  const float* hw   = (const float*)d_in[10];
  const float* hb   = (const float*)d_in[11];
  const float* how  = (const float*)d_in[12];
  const float* hob  = (const float*)d_in[13];
  float* out = (float*)d_out;

  // ---- workspace carve (~92 MB): rotating weight bufs + per-chunk scratch ----
  char* p = (char*)d_ws;
  _Float16* wip  = (_Float16*)p; p += (size_t)2402304 * 2;  // 3128*768 (also how-packed)
  _Float16* wop  = (_Float16*)p; p += (size_t)1179648 * 2;  // 768*1536 (also hw)
  float*    hob_p = (float*)p;   p += (size_t)1024 * 4;
  _Float16* xbuf = (_Float16*)p; p += (size_t)BATCH * L_SEQ * DIMM * 2;  // persistent per chunk
  _Float16* zx   = (_Float16*)p; p += (size_t)L_SEQ * ZXP * 2;           // shared scratch
  float*    xbc  = (float*)p;    p += (size_t)L_SEQ * CONVD * 4;
  float*    Hseg = (float*)p;    p += (size_t)NHEADS * NSEG * 1024 * 4;
  float*    dtp  = (float*)p;    p += (size_t)L_SEQ * NHEADS * 4;
  float*    dap  = (float*)p;    p += (size_t)L_SEQ * NHEADS * 4;
  float*    cumq = (float*)p;    p += (size_t)L_SEQ * NHEADS * 4;
  (void)ws_size;

  // input conversion (all 4 batches)
  cvt_kernel<<<6144, 256, 0, stream>>>(x_in, xbuf, (long)BATCH * L_SEQ * DIMM / 4);

  // ---- layer-major: weights converted once per layer, chunks inner ----
  for (int i = 0; i < 6; ++i) {
    cvt_kernel<<<2346, 256, 0, stream>>>(ipw + (size_t)i * D_IPROJ * DIMM, wip,
                                         (long)D_IPROJ * DIMM / 4);
    cvt_kernel<<<1152, 256, 0, stream>>>(opw + (size_t)i * DIMM * D_INNER, wop,
                                         (long)DIMM * D_INNER / 4);
    for (int c = 0; c < BATCH; ++c) {
      _Float16* xc = xbuf + (size_t)c * L_SEQ * DIMM;
      gemm_mfma<0><<<dim3((D_IPROJ + 127) / 128, L_SEQ / 128), 256, 0, stream>>>(
          xc, DIMM, wip, nullptr, zx, ZXP, 0, L_SEQ, D_IPROJ, DIMM, nullptr, 0);
      dt_kernel<<<(L_SEQ * NHEADS) / 256, 256, 0, stream>>>(
          zx, dtb + i * NHEADS, alog + i * NHEADS, dtp, dap, L_SEQ * NHEADS);
      conv_kernel<<<(L_SEQ * CONVD) / 256, 256, 0, stream>>>(
          zx, cw + (size_t)i * CONVD * 4, cb + i * CONVD, xbc);
      scanA_kernel<<<NHEADS * NSEG, 64, 0, stream>>>(
          xbc, dtp, dap, Dv + i * NHEADS, Hseg, cumq);
      scanB_kernel<<<NHEADS, 64, 0, stream>>>(Hseg, cumq);
      scanC_kernel<<<NHEADS * NSEG, 64, 0, stream>>>(xbc, Hseg, cumq);
      norm_kernel<<<L_SEQ, 256, 0, stream>>>(xbc, zx, nw + i * D_INNER);
      gemm_mfma<0><<<dim3(DIMM / 128, L_SEQ / 128), 256, 0, stream>>>(
          zx, ZXP, wop, nullptr, xc, DIMM, 0, L_SEQ, DIMM, D_INNER, nullptr, 0);
    }
  }

  // ---- heads: per t convert weights once, chunks inner ----
  for (int t = 0; t < 2; ++t) {
    cvt_kernel<<<576, 256, 0, stream>>>(hw + (size_t)t * DIMM * DIMM, wop,
                                        (long)DIMM * DIMM / 4);
    pack_head_t<<<1536, 256, 0, stream>>>(how, hob, wip, hob_p, t);
    for (int c = 0; c < BATCH; ++c) {
      _Float16* xc = xbuf + (size_t)c * L_SEQ * DIMM;
      _Float16* hbuf = zx;   // scratch reuse, dense [L_SEQ][768]
      gemm_mfma<2><<<dim3(DIMM / 128, L_SEQ / 128), 256, 0, stream>>>(
          xc, DIMM, wop, hb + t * DIMM, hbuf, DIMM, 0, L_SEQ, DIMM, DIMM,
          nullptr, 0);
      gemm_mfma<3><<<dim3(4, L_SEQ / 128), 256, 0, stream>>>(
          hbuf, DIMM, wip, hob_p + t * 512,
          out + (size_t)t * 4 * (BATCH * L_SEQ) * 128 + (size_t)c * L_SEQ * 128,
          128, (long)(BATCH * L_SEQ) * 128, L_SEQ, 512, DIMM,
          tids + (size_t)c * L_SEQ, t);
    }
  }
}

// Round 9
// 3096.354 us; speedup vs baseline: 2.8986x; 2.8986x over previous
//
#include <hip/hip_runtime.h>
#include <cstdint>
#include <cstddef>

#define L_SEQ   4096
#define BATCH   4
#define DIMM    768
#define D_INNER 1536
#define NHEADS  24
#define HEADDIM 64
#define D_STATE 16
#define CONVD   1568
#define D_IPROJ 3128
#define ZXP     3200     // padded zx row stride (6400B = 64B-aligned rows)
#define SEGLEN  64
#define NSEG    (L_SEQ / SEGLEN)   // 64

typedef _Float16 f16x8 __attribute__((ext_vector_type(8)));
typedef _Float16 f16x4 __attribute__((ext_vector_type(4)));
typedef float    f32x4 __attribute__((ext_vector_type(4)));

// Direct global->LDS async copy, 16B per lane. LDS dest = uniform base + lane*16.
__device__ __forceinline__ void glds16(const _Float16* g, _Float16* l) {
  __builtin_amdgcn_global_load_lds(
      (__attribute__((address_space(1))) unsigned int*)g,
      (__attribute__((address_space(3))) unsigned int*)l, 16, 0, 0);
}

// ---------------------------------------------------------------------------
// f16 MFMA GEMM: C[m,n] = sum_k A[m*lda+k]*W[n*K+k] (+bias). 128x128x64 tile,
// 4 waves (2x2), 16x16x32 MFMA. Staging via global_load_lds (NO register
// staging -> no spill). XOR bank-swizzle realized by pre-swizzling the
// per-lane GLOBAL source address; LDS writes stay linear (rule 21).
// OM: 0 = f16 out (+ col<N guard), 2 = f16 out + f32 bias,
//     3 = f32 out + bias + sigmoid(q>0) + type-mask (head fusion; N=512)
// ---------------------------------------------------------------------------
template <int OM>
__global__ __launch_bounds__(256, 2) void gemm_mfma(
    const _Float16* __restrict__ A, int lda,
    const _Float16* __restrict__ W,
    const float* __restrict__ bias,
    void* __restrict__ Cv, long ldc, long extra,
    int M, int N, int K,
    const int* __restrict__ tidsp, int thead)
{
  __shared__ __align__(16) char smem[33792];
  _Float16* As = (_Float16*)smem;              // [128][64] f16, linear
  _Float16* Ws = (_Float16*)(smem + 16384);
  const int tid = threadIdx.x;
  const int lane = tid & 63, wid = tid >> 6;
  const int wr = wid >> 1, wc = wid & 1;

  // ---- XCD-band block swizzle ----
  const int nbx = gridDim.x, nby = gridDim.y;
  const int flat = blockIdx.y * nbx + blockIdx.x;
  const int xcd = flat & 7;
  const int bidx = flat >> 3;
  const int rpx = nby >> 3;             // row-tiles per XCD
  const int rl = bidx % rpx;
  const int ct = bidx / rpx;
  const long m0 = (long)(xcd * rpx + rl) * 128;
  const int n0 = ct * 128;

  const int la = lane & 15, lg = lane >> 4;
  const int srow = lane >> 3, schunk = lane & 7;

  f32x4 acc[4][4] = {};

  for (int k0 = 0; k0 < K; k0 += 64) {
    __syncthreads();                    // prior compute done reading LDS
#pragma unroll
    for (int p = 0; p < 4; ++p) {
      const int rg = (wid << 2) + p;            // 0..15 (wave-uniform)
      const int row = (rg << 3) + srow;         // local tile row 0..127
      const int scn = schunk ^ (row & 7);       // pre-swizzled k-chunk
      glds16(A + (m0 + row) * (long)lda + k0 + scn * 8, As + rg * 512);
      int n = n0 + row; if (n >= N) n = N - 1;  // clamp (garbage cols unstored)
      glds16(W + (long)n * K + k0 + scn * 8, Ws + rg * 512);
    }
    asm volatile("s_waitcnt vmcnt(0)" ::: "memory");
    __syncthreads();
#pragma unroll
    for (int ks = 0; ks < 2; ++ks) {
      const int cc = ks * 4 + lg;
      f16x8 af[4], bfr[4];
#pragma unroll
      for (int i = 0; i < 4; ++i) {
        int ra = wr * 64 + i * 16 + la;
        int rb = wc * 64 + i * 16 + la;
        af[i]  = *(const f16x8*)&As[ra * 64 + ((cc ^ (ra & 7)) << 3)];
        bfr[i] = *(const f16x8*)&Ws[rb * 64 + ((cc ^ (rb & 7)) << 3)];
      }
#pragma unroll
      for (int i = 0; i < 4; ++i)
#pragma unroll
        for (int j = 0; j < 4; ++j)
          acc[i][j] = __builtin_amdgcn_mfma_f32_16x16x32_f16(af[i], bfr[j], acc[i][j], 0, 0, 0);
    }
  }

  // ---- epilogue via LDS transpose (2 phases of 64 rows) ----
  float* epi = (float*)smem;                    // [64][132]
#pragma unroll
  for (int ph = 0; ph < 2; ++ph) {
    __syncthreads();
    if (wr == ph) {
#pragma unroll
      for (int i = 0; i < 4; ++i)
#pragma unroll
        for (int j = 0; j < 4; ++j)
#pragma unroll
          for (int r = 0; r < 4; ++r)
            epi[(i * 16 + lg * 4 + r) * 132 + wc * 64 + j * 16 + la] = acc[i][j][r];
    }
    __syncthreads();
    if (OM == 3) {
      const int q = n0 >> 7;
      const int rr = tid >> 5;        // 0..7
      const int ch = tid & 31;        // 16B chunk within row
#pragma unroll
      for (int ps = 0; ps < 8; ++ps) {
        int lrow = ps * 8 + rr;
        long gr = m0 + ph * 64 + lrow;
        float keep = (tidsp[gr] == thead) ? 1.f : 0.f;
        float4 v = *(float4*)&epi[lrow * 132 + ch * 4];
        float o[4] = {v.x, v.y, v.z, v.w};
#pragma unroll
        for (int e = 0; e < 4; ++e) {
          float vv = o[e] + bias[n0 + ch * 4 + e];
          if (q != 0) vv = 1.f / (1.f + expf(-vv));
          o[e] = vv * keep;
        }
        *(float4*)((float*)Cv + (long)q * extra + gr * 128 + ch * 4) =
            make_float4(o[0], o[1], o[2], o[3]);
      }
    } else {
      const int rr = tid >> 4;        // 0..15
      const int ch = tid & 15;        // 16B (8-f16) chunk
      const int col = n0 + ch * 8;
      float b[8] = {0.f, 0.f, 0.f, 0.f, 0.f, 0.f, 0.f, 0.f};
      if (OM == 2 && col < N) {
#pragma unroll
        for (int e = 0; e < 8; ++e) b[e] = bias[col + e];
      }
#pragma unroll
      for (int ps = 0; ps < 4; ++ps) {
        int lrow = ps * 16 + rr;
        long gr = m0 + ph * 64 + lrow;
        if (col < N) {
          float4 v0 = *(float4*)&epi[lrow * 132 + ch * 8];
          float4 v1 = *(float4*)&epi[lrow * 132 + ch * 8 + 4];
          f16x8 o = {(_Float16)(v0.x + b[0]), (_Float16)(v0.y + b[1]),
                     (_Float16)(v0.z + b[2]), (_Float16)(v0.w + b[3]),
                     (_Float16)(v1.x + b[4]), (_Float16)(v1.y + b[5]),
                     (_Float16)(v1.z + b[6]), (_Float16)(v1.w + b[7])};
          *(f16x8*)((_Float16*)Cv + gr * ldc + col) = o;
        }
      }
    }
  }
}

// ---------------------------------------------------------------------------
__global__ __launch_bounds__(256) void cvt_kernel(
    const float* __restrict__ src, _Float16* __restrict__ dst, long n4)
{
  long i = (long)blockIdx.x * 256 + threadIdx.x;
  long stride = (long)gridDim.x * 256;
  for (; i < n4; i += stride) {
    float4 v = *(const float4*)(src + i * 4);
    f16x4 o = { (_Float16)v.x, (_Float16)v.y, (_Float16)v.z, (_Float16)v.w };
    *(f16x4*)(dst + i * 4) = o;
  }
}

// how [2][4][128][768] -> packed [2][512][768] in output order; hob likewise.
__global__ __launch_bounds__(256) void pack_head_kernel(
    const float* __restrict__ how, const float* __restrict__ hob,
    _Float16* __restrict__ howb, float* __restrict__ hobp)
{
  const int wmap[4] = {0, 3, 1, 2};
  int idx = blockIdx.x * 256 + threadIdx.x;
  if (idx < 2 * 512 * 768) {
    int t = idx / (512 * 768);
    int rem = idx - t * 512 * 768;
    int q = rem / (128 * 768);
    int rem2 = rem - q * 128 * 768;
    howb[idx] = (_Float16)how[((size_t)(t * 4 + wmap[q])) * 128 * 768 + rem2];
  }
  if (idx < 1024) {
    int t = idx >> 9, rem = idx & 511;
    int q = rem >> 7, pp = rem & 127;
    hobp[idx] = hob[(t * 4 + wmap[q]) * 128 + pp];
  }
}

// ---------------------------------------------------------------------------
__global__ __launch_bounds__(256) void dt_kernel(
    const _Float16* __restrict__ zx, const float* __restrict__ dtb,
    const float* __restrict__ alog, float* __restrict__ dtp,
    float* __restrict__ dap, int total)
{
  int idx = blockIdx.x * 256 + threadIdx.x;
  if (idx >= total) return;
  int bl = idx / NHEADS, hh = idx - bl * NHEADS;
  float raw = (float)zx[(size_t)bl * ZXP + (D_INNER + CONVD) + hh] + dtb[hh];
  float sp = (raw > 20.f) ? raw : log1pf(expf(raw));
  dtp[idx] = sp;
  dap[idx] = expf(-expf(alog[hh]) * sp);
}

__global__ __launch_bounds__(256) void conv_kernel(
    const _Float16* __restrict__ zx, const float* __restrict__ cw,
    const float* __restrict__ cb, float* __restrict__ xbc)
{
  int idx = blockIdx.x * 256 + threadIdx.x;
  int bl = idx / CONVD;
  int c = idx - bl * CONVD;
  int l = bl & (L_SEQ - 1);   // position within its batch
  float acc = cb[c];
#pragma unroll
  for (int k = 0; k < 4; ++k) {
    int ls = l - 3 + k;
    if (ls >= 0)
      acc = fmaf(cw[c * 4 + k],
                 (float)zx[(size_t)(bl - 3 + k) * ZXP + D_INNER + c], acc);
  }
  xbc[(size_t)bl * CONVD + c] = acc / (1.f + expf(-acc));
}

// ---------------------------------------------------------------------------
// Scan pass A: per (b,h,seg) local scan (h0=0).
// ---------------------------------------------------------------------------
__global__ __launch_bounds__(64) void scanA_kernel(
    float* __restrict__ xbc, const float* __restrict__ dtp,
    const float* __restrict__ dap, const float* __restrict__ Dv,
    float* __restrict__ Hseg, float* __restrict__ cumq)
{
  __shared__ float sbc[SEGLEN][32];
  __shared__ float sdt[SEGLEN], sda[SEGLEN];
  const int lane = threadIdx.x;
  const int seg = blockIdx.x & (NSEG - 1);
  const int bh = blockIdx.x >> 6;
  const int h = bh % NHEADS, b = bh / NHEADS;
  const float Dh = Dv[h];
  const int bl0 = b * L_SEQ + seg * SEGLEN;

  for (int i = lane; i < SEGLEN * 8; i += 64) {
    int t = i >> 3, q = (i & 7) << 2;
    *(float4*)&sbc[t][q] = *(const float4*)&xbc[(size_t)(bl0 + t) * CONVD + D_INNER + q];
  }
  sdt[lane] = dtp[(size_t)(bl0 + lane) * NHEADS + h];
  float myda = dap[(size_t)(bl0 + lane) * NHEADS + h];
  sda[lane] = myda;
  __syncthreads();

  float pp = myda;
#pragma unroll
  for (int off = 1; off < 64; off <<= 1) {
    float tv = __shfl_up(pp, off, 64);
    if (lane >= off) pp *= tv;
  }
  cumq[(size_t)bh * L_SEQ + seg * SEGLEN + lane] = pp;

  float hs[16];
#pragma unroll
  for (int n = 0; n < 16; ++n) hs[n] = 0.f;

  size_t xaddr = (size_t)bl0 * CONVD + h * HEADDIM + lane;
  float xv = xbc[xaddr];
  for (int t = 0; t < SEGLEN; ++t) {
    float xn = (t < SEGLEN - 1) ? xbc[xaddr + CONVD] : 0.f;
    float dav = sda[t];
    float coef = sdt[t] * xv;
    float y0 = 0.f, y1 = 0.f, y2 = 0.f, y3 = 0.f;
#pragma unroll
    for (int n = 0; n < 16; ++n) {
      float hv = fmaf(hs[n], dav, coef * sbc[t][n]);
      hs[n] = hv;
      float cvv = sbc[t][16 + n];
      if ((n & 3) == 0)      y0 = fmaf(hv, cvv, y0);
      else if ((n & 3) == 1) y1 = fmaf(hv, cvv, y1);
      else if ((n & 3) == 2) y2 = fmaf(hv, cvv, y2);
      else                   y3 = fmaf(hv, cvv, y3);
    }
    xbc[xaddr] = fmaf(Dh, xv, (y0 + y1) + (y2 + y3));
    xv = xn;
    xaddr += CONVD;
  }

  float* Hst = Hseg + ((size_t)bh * NSEG + seg) * 1024 + lane * 16;
#pragma unroll
  for (int n = 0; n < 16; n += 4)
    *(float4*)&Hst[n] = make_float4(hs[n], hs[n + 1], hs[n + 2], hs[n + 3]);
}

// Pass B: per (b,h) combine across segments; Hseg slot becomes ENTRY state.
__global__ __launch_bounds__(64) void scanB_kernel(
    float* __restrict__ Hseg, const float* __restrict__ cumq)
{
  const int lane = threadIdx.x;
  const int bh = blockIdx.x;
  float hin[16];
#pragma unroll
  for (int n = 0; n < 16; ++n) hin[n] = 0.f;
  for (int s = 0; s < NSEG; ++s) {
    float* slot = Hseg + ((size_t)bh * NSEG + s) * 1024 + lane * 16;
    float P = cumq[(size_t)bh * L_SEQ + s * SEGLEN + (SEGLEN - 1)];
    float hl[16];
#pragma unroll
    for (int n = 0; n < 16; n += 4) {
      float4 v = *(float4*)(slot + n);
      hl[n] = v.x; hl[n + 1] = v.y; hl[n + 2] = v.z; hl[n + 3] = v.w;
    }
#pragma unroll
    for (int n = 0; n < 16; n += 4)
      *(float4*)(slot + n) = make_float4(hin[n], hin[n + 1], hin[n + 2], hin[n + 3]);
#pragma unroll
    for (int n = 0; n < 16; ++n) hin[n] = fmaf(P, hin[n], hl[n]);
  }
}

// Pass C: y += cumprod * (C . h_entry)
__global__ __launch_bounds__(64) void scanC_kernel(
    float* __restrict__ xbc, const float* __restrict__ Hseg,
    const float* __restrict__ cumq)
{
  const int seg = blockIdx.x & (NSEG - 1);
  if (seg == 0) return;
  __shared__ float sc[SEGLEN][16];
  __shared__ float scq[SEGLEN];
  const int lane = threadIdx.x;
  const int bh = blockIdx.x >> 6;
  const int h = bh % NHEADS, b = bh / NHEADS;
  const int bl0 = b * L_SEQ + seg * SEGLEN;
  const float* slot = Hseg + ((size_t)bh * NSEG + seg) * 1024 + lane * 16;
  float hin[16];
#pragma unroll
  for (int n = 0; n < 16; n += 4) {
    float4 v = *(const float4*)(slot + n);
    hin[n] = v.x; hin[n + 1] = v.y; hin[n + 2] = v.z; hin[n + 3] = v.w;
  }
  for (int i = lane; i < SEGLEN * 4; i += 64) {
    int t = i >> 2, q = (i & 3) << 2;
    *(float4*)&sc[t][q] =
        *(const float4*)&xbc[(size_t)(bl0 + t) * CONVD + D_INNER + D_STATE + q];
  }
  scq[lane] = cumq[(size_t)bh * L_SEQ + seg * SEGLEN + lane];
  __syncthreads();
  for (int t = 0; t < SEGLEN; ++t) {
    float dot = 0.f;
#pragma unroll
    for (int n = 0; n < 16; ++n) dot = fmaf(hin[n], sc[t][n], dot);
    size_t ad = (size_t)(bl0 + t) * CONVD + h * HEADDIM + lane;
    xbc[ad] = fmaf(scq[t], dot, xbc[ad]);
  }
}

// ---------------------------------------------------------------------------
// y *= silu(z); RMS-norm over 1536; * norm_w; f16 result overwrites zx cols
// 0..1535 of the same row (read-then-write within one block => safe).
// ---------------------------------------------------------------------------
__global__ __launch_bounds__(256) void norm_kernel(
    const float* __restrict__ y, _Float16* __restrict__ zx,
    const float* __restrict__ nw)
{
  const int row = blockIdx.x;
  const int tid = threadIdx.x;
  const float* yr = y + (size_t)row * CONVD;
  _Float16* zr = zx + (size_t)row * ZXP;
  float v[6];
  float ss = 0.f;
#pragma unroll
  for (int jj = 0; jj < 6; ++jj) {
    int c = jj * 256 + tid;
    float yv = yr[c];
    float zv = (float)zr[c];
    float sz = zv / (1.f + expf(-zv));
    float val = yv * sz;
    v[jj] = val;
    ss = fmaf(val, val, ss);
  }
#pragma unroll
  for (int off = 32; off > 0; off >>= 1) ss += __shfl_xor(ss, off, 64);
  __shared__ float red[4];
  if ((tid & 63) == 0) red[tid >> 6] = ss;
  __syncthreads();
  float tot = red[0] + red[1] + red[2] + red[3];
  float rs = rsqrtf(tot * (1.f / 1536.f) + 1e-5f);
#pragma unroll
  for (int jj = 0; jj < 6; ++jj) {
    int c = jj * 256 + tid;
    zr[c] = (_Float16)(v[jj] * rs * nw[c]);
  }
}

// ---------------------------------------------------------------------------
extern "C" void kernel_launch(void* const* d_in, const int* in_sizes, int n_in,
                              void* d_out, int out_size, void* d_ws, size_t ws_size,
                              hipStream_t stream)
{
  const float* x_in = (const float*)d_in[0];
  const int*   tids = (const int*)d_in[1];
  const float* ipw  = (const float*)d_in[2];
  const float* cw   = (const float*)d_in[3];
  const float* cb   = (const float*)d_in[4];
  const float* dtb  = (const float*)d_in[5];
  const float* alog = (const float*)d_in[6];
  const float* Dv   = (const float*)d_in[7];
  const float* nw   = (const float*)d_in[8];
  const float* opw  = (const float*)d_in[9];
  const float* hw   = (const float*)d_in[10];
  const float* hb   = (const float*)d_in[11];
  const float* how  = (const float*)d_in[12];
  const float* hob  = (const float*)d_in[13];
  float* out = (float*)d_out;

  // ---- workspace carve: f16 weights (upfront) + per-chunk activations ----
  char* p = (char*)d_ws;
  _Float16* ipw_b = (_Float16*)p; p += (size_t)14413824 * 2;  // 6*3128*768
  _Float16* opw_b = (_Float16*)p; p += (size_t)7077888 * 2;   // 6*768*1536
  _Float16* hw_b  = (_Float16*)p; p += (size_t)1179648 * 2;   // 2*768*768
  _Float16* how_b = (_Float16*)p; p += (size_t)786432 * 2;    // 2*512*768
  float*    hob_p = (float*)p;    p += (size_t)1024 * 4;
  const size_t used_w = (size_t)(p - (char*)d_ws);
  // per batch: zx 26.2MB + xbc 25.7MB + Hseg 6.3MB + dt/da/cumq 1.2MB + xbuf 6.3MB
  const size_t PB = 65667072;
  int nb = 4;
  while (nb > 1 && used_w + (size_t)nb * PB > ws_size) nb >>= 1;

  // ---- weight conversions (idempotent, every launch) ----
  cvt_kernel<<<8192, 256, 0, stream>>>(ipw, ipw_b, 14413824 / 4);
  cvt_kernel<<<6912, 256, 0, stream>>>(opw, opw_b, 7077888 / 4);
  cvt_kernel<<<1152, 256, 0, stream>>>(hw, hw_b, 1179648 / 4);
  pack_head_kernel<<<3072, 256, 0, stream>>>(how, hob, how_b, hob_p);

  for (int b0 = 0; b0 < BATCH; b0 += nb) {
    const int MT = nb * L_SEQ;
    _Float16* zx  = (_Float16*)p;
    float* xbc  = (float*)(zx + (size_t)MT * ZXP);
    float* Hseg = xbc + (size_t)MT * CONVD;
    float* dtp  = Hseg + (size_t)nb * NHEADS * NSEG * 1024;
    float* dap  = dtp + (size_t)MT * NHEADS;
    float* cumq = dap + (size_t)MT * NHEADS;
    _Float16* xbuf = (_Float16*)(cumq + (size_t)MT * NHEADS);
    _Float16* hbuf = zx;   // head hidden, dense [MT][768]; zx dead at head stage

    cvt_kernel<<<6144, 256, 0, stream>>>(x_in + (size_t)b0 * L_SEQ * DIMM,
                                         xbuf, (long)MT * DIMM / 4);

    for (int i = 0; i < 6; ++i) {
      gemm_mfma<0><<<dim3((D_IPROJ + 127) / 128, MT / 128), 256, 0, stream>>>(
          xbuf, DIMM, ipw_b + (size_t)i * D_IPROJ * DIMM, nullptr,
          zx, ZXP, 0, MT, D_IPROJ, DIMM, nullptr, 0);
      dt_kernel<<<(MT * NHEADS + 255) / 256, 256, 0, stream>>>(
          zx, dtb + i * NHEADS, alog + i * NHEADS, dtp, dap, MT * NHEADS);
      conv_kernel<<<(MT * CONVD) / 256, 256, 0, stream>>>(
          zx, cw + (size_t)i * CONVD * 4, cb + i * CONVD, xbc);
      scanA_kernel<<<nb * NHEADS * NSEG, 64, 0, stream>>>(
          xbc, dtp, dap, Dv + i * NHEADS, Hseg, cumq);
      scanB_kernel<<<nb * NHEADS, 64, 0, stream>>>(Hseg, cumq);
      scanC_kernel<<<nb * NHEADS * NSEG, 64, 0, stream>>>(xbc, Hseg, cumq);
      norm_kernel<<<MT, 256, 0, stream>>>(xbc, zx, nw + i * D_INNER);
      gemm_mfma<0><<<dim3(DIMM / 128, MT / 128), 256, 0, stream>>>(
          zx, ZXP, opw_b + (size_t)i * DIMM * D_INNER, nullptr,
          xbuf, DIMM, 0, MT, DIMM, D_INNER, nullptr, 0);
    }

    for (int t = 0; t < 2; ++t) {
      gemm_mfma<2><<<dim3(DIMM / 128, MT / 128), 256, 0, stream>>>(
          xbuf, DIMM, hw_b + (size_t)t * DIMM * DIMM, hb + t * DIMM,
          hbuf, DIMM, 0, MT, DIMM, DIMM, nullptr, 0);
      gemm_mfma<3><<<dim3(4, MT / 128), 256, 0, stream>>>(
          hbuf, DIMM, how_b + (size_t)t * 512 * DIMM, hob_p + t * 512,
          out + (size_t)t * 4 * 16384 * 128 + (size_t)b0 * L_SEQ * 128,
          128, (long)16384 * 128, MT, 512, DIMM,
          tids + (size_t)b0 * L_SEQ, t);
    }
  }
}

// Round 10
// 2996.438 us; speedup vs baseline: 2.9952x; 1.0333x over previous
//
#include <hip/hip_runtime.h>
#include <cstdint>
#include <cstddef>

#define L_SEQ   4096
#define BATCH   4
#define DIMM    768
#define D_INNER 1536
#define NHEADS  24
#define HEADDIM 64
#define D_STATE 16
#define CONVD   1568
#define D_IPROJ 3128
#define ZXP     3200     // padded zx row stride (6400B = 64B-aligned rows)
#define SEGLEN  64
#define NSEG    (L_SEQ / SEGLEN)   // 64

typedef _Float16 f16x8 __attribute__((ext_vector_type(8)));
typedef _Float16 f16x4 __attribute__((ext_vector_type(4)));
typedef float    f32x4 __attribute__((ext_vector_type(4)));

// Direct global->LDS async copy, 16B per lane. LDS dest = uniform base + lane*16.
__device__ __forceinline__ void glds16(const _Float16* g, _Float16* l) {
  __builtin_amdgcn_global_load_lds(
      (__attribute__((address_space(1))) unsigned int*)g,
      (__attribute__((address_space(3))) unsigned int*)l, 16, 0, 0);
}

// ---------------------------------------------------------------------------
// f16 MFMA GEMM (round-9 structure, unchanged): 128x128x64 tile, 4 waves,
// global_load_lds staging (no register staging -> no spill), XOR swizzle via
// pre-swizzled global source, XCD-band block swizzle, LDS-transpose epilogue.
// OM: 0 = f16 out (+ col<N guard), 2 = f16 out + f32 bias,
//     3 = f32 out + bias + sigmoid(q>0) + type-mask (head fusion; N=512)
// ---------------------------------------------------------------------------
template <int OM>
__global__ __launch_bounds__(256, 2) void gemm_mfma(
    const _Float16* __restrict__ A, int lda,
    const _Float16* __restrict__ W,
    const float* __restrict__ bias,
    void* __restrict__ Cv, long ldc, long extra,
    int M, int N, int K,
    const int* __restrict__ tidsp, int thead)
{
  __shared__ __align__(16) char smem[33792];
  _Float16* As = (_Float16*)smem;              // [128][64] f16, linear
  _Float16* Ws = (_Float16*)(smem + 16384);
  const int tid = threadIdx.x;
  const int lane = tid & 63, wid = tid >> 6;
  const int wr = wid >> 1, wc = wid & 1;

  const int nbx = gridDim.x, nby = gridDim.y;
  const int flat = blockIdx.y * nbx + blockIdx.x;
  const int xcd = flat & 7;
  const int bidx = flat >> 3;
  const int rpx = nby >> 3;
  const int rl = bidx % rpx;
  const int ct = bidx / rpx;
  const long m0 = (long)(xcd * rpx + rl) * 128;
  const int n0 = ct * 128;

  const int la = lane & 15, lg = lane >> 4;
  const int srow = lane >> 3, schunk = lane & 7;

  f32x4 acc[4][4] = {};

  for (int k0 = 0; k0 < K; k0 += 64) {
    __syncthreads();
#pragma unroll
    for (int p = 0; p < 4; ++p) {
      const int rg = (wid << 2) + p;
      const int row = (rg << 3) + srow;
      const int scn = schunk ^ (row & 7);
      glds16(A + (m0 + row) * (long)lda + k0 + scn * 8, As + rg * 512);
      int n = n0 + row; if (n >= N) n = N - 1;
      glds16(W + (long)n * K + k0 + scn * 8, Ws + rg * 512);
    }
    asm volatile("s_waitcnt vmcnt(0)" ::: "memory");
    __syncthreads();
#pragma unroll
    for (int ks = 0; ks < 2; ++ks) {
      const int cc = ks * 4 + lg;
      f16x8 af[4], bfr[4];
#pragma unroll
      for (int i = 0; i < 4; ++i) {
        int ra = wr * 64 + i * 16 + la;
        int rb = wc * 64 + i * 16 + la;
        af[i]  = *(const f16x8*)&As[ra * 64 + ((cc ^ (ra & 7)) << 3)];
        bfr[i] = *(const f16x8*)&Ws[rb * 64 + ((cc ^ (rb & 7)) << 3)];
      }
#pragma unroll
      for (int i = 0; i < 4; ++i)
#pragma unroll
        for (int j = 0; j < 4; ++j)
          acc[i][j] = __builtin_amdgcn_mfma_f32_16x16x32_f16(af[i], bfr[j], acc[i][j], 0, 0, 0);
    }
  }

  float* epi = (float*)smem;                    // [64][132]
#pragma unroll
  for (int ph = 0; ph < 2; ++ph) {
    __syncthreads();
    if (wr == ph) {
#pragma unroll
      for (int i = 0; i < 4; ++i)
#pragma unroll
        for (int j = 0; j < 4; ++j)
#pragma unroll
          for (int r = 0; r < 4; ++r)
            epi[(i * 16 + lg * 4 + r) * 132 + wc * 64 + j * 16 + la] = acc[i][j][r];
    }
    __syncthreads();
    if (OM == 3) {
      const int q = n0 >> 7;
      const int rr = tid >> 5;
      const int ch = tid & 31;
#pragma unroll
      for (int ps = 0; ps < 8; ++ps) {
        int lrow = ps * 8 + rr;
        long gr = m0 + ph * 64 + lrow;
        float keep = (tidsp[gr] == thead) ? 1.f : 0.f;
        float4 v = *(float4*)&epi[lrow * 132 + ch * 4];
        float o[4] = {v.x, v.y, v.z, v.w};
#pragma unroll
        for (int e = 0; e < 4; ++e) {
          float vv = o[e] + bias[n0 + ch * 4 + e];
          if (q != 0) vv = 1.f / (1.f + expf(-vv));
          o[e] = vv * keep;
        }
        *(float4*)((float*)Cv + (long)q * extra + gr * 128 + ch * 4) =
            make_float4(o[0], o[1], o[2], o[3]);
      }
    } else {
      const int rr = tid >> 4;
      const int ch = tid & 15;
      const int col = n0 + ch * 8;
      float b[8] = {0.f, 0.f, 0.f, 0.f, 0.f, 0.f, 0.f, 0.f};
      if (OM == 2 && col < N) {
#pragma unroll
        for (int e = 0; e < 8; ++e) b[e] = bias[col + e];
      }
#pragma unroll
      for (int ps = 0; ps < 4; ++ps) {
        int lrow = ps * 16 + rr;
        long gr = m0 + ph * 64 + lrow;
        if (col < N) {
          float4 v0 = *(float4*)&epi[lrow * 132 + ch * 8];
          float4 v1 = *(float4*)&epi[lrow * 132 + ch * 8 + 4];
          f16x8 o = {(_Float16)(v0.x + b[0]), (_Float16)(v0.y + b[1]),
                     (_Float16)(v0.z + b[2]), (_Float16)(v0.w + b[3]),
                     (_Float16)(v1.x + b[4]), (_Float16)(v1.y + b[5]),
                     (_Float16)(v1.z + b[6]), (_Float16)(v1.w + b[7])};
          *(f16x8*)((_Float16*)Cv + gr * ldc + col) = o;
        }
      }
    }
  }
}

// ---------------------------------------------------------------------------
__global__ __launch_bounds__(256) void cvt_kernel(
    const float* __restrict__ src, _Float16* __restrict__ dst, long n4)
{
  long i = (long)blockIdx.x * 256 + threadIdx.x;
  long stride = (long)gridDim.x * 256;
  for (; i < n4; i += stride) {
    float4 v = *(const float4*)(src + i * 4);
    f16x4 o = { (_Float16)v.x, (_Float16)v.y, (_Float16)v.z, (_Float16)v.w };
    *(f16x4*)(dst + i * 4) = o;
  }
}

__global__ __launch_bounds__(256) void pack_head_kernel(
    const float* __restrict__ how, const float* __restrict__ hob,
    _Float16* __restrict__ howb, float* __restrict__ hobp)
{
  const int wmap[4] = {0, 3, 1, 2};
  int idx = blockIdx.x * 256 + threadIdx.x;
  if (idx < 2 * 512 * 768) {
    int t = idx / (512 * 768);
    int rem = idx - t * 512 * 768;
    int q = rem / (128 * 768);
    int rem2 = rem - q * 128 * 768;
    howb[idx] = (_Float16)how[((size_t)(t * 4 + wmap[q])) * 128 * 768 + rem2];
  }
  if (idx < 1024) {
    int t = idx >> 9, rem = idx & 511;
    int q = rem >> 7, pp = rem & 127;
    hobp[idx] = hob[(t * 4 + wmap[q]) * 128 + pp];
  }
}

// ---------------------------------------------------------------------------
// Fused conv(4)+silu (8 channels/thread, f16x8) + dt/dA (cg<3 threads).
// Writes xbc as f16 [MT][1568].
// ---------------------------------------------------------------------------
#define CGRP 196   // 1568/8 channel groups
__global__ __launch_bounds__(256) void conv_dt_kernel(
    const _Float16* __restrict__ zx, const float* __restrict__ cw,
    const float* __restrict__ cb, _Float16* __restrict__ xbc,
    const float* __restrict__ dtb, const float* __restrict__ alog,
    float* __restrict__ dtp, float* __restrict__ dap)
{
  int idx = blockIdx.x * 256 + threadIdx.x;
  int bl = idx / CGRP;
  int cg = idx - bl * CGRP;
  int l = bl & (L_SEQ - 1);
  const int c0 = cg * 8;

  float acc[8];
#pragma unroll
  for (int e = 0; e < 8; ++e) acc[e] = cb[c0 + e];
#pragma unroll
  for (int k = 0; k < 4; ++k) {
    int ls = l - 3 + k;
    if (ls >= 0) {
      f16x8 v = *(const f16x8*)&zx[(size_t)(bl - 3 + k) * ZXP + D_INNER + c0];
#pragma unroll
      for (int e = 0; e < 8; ++e)
        acc[e] = fmaf(cw[(c0 + e) * 4 + k], (float)v[e], acc[e]);
    }
  }
  f16x8 o;
#pragma unroll
  for (int e = 0; e < 8; ++e) {
    float s = acc[e] / (1.f + expf(-acc[e]));
    o[e] = (_Float16)s;
  }
  *(f16x8*)&xbc[(size_t)bl * CONVD + c0] = o;

  if (cg < 3) {   // dt/dA for heads c0..c0+7 (24 total)
    f16x8 rw = *(const f16x8*)&zx[(size_t)bl * ZXP + (D_INNER + CONVD) + c0];
#pragma unroll
    for (int e = 0; e < 8; ++e) {
      int hh = c0 + e;
      float raw = (float)rw[e] + dtb[hh];
      float sp = (raw > 20.f) ? raw : log1pf(expf(raw));
      dtp[(size_t)bl * NHEADS + hh] = sp;
      dap[(size_t)bl * NHEADS + hh] = expf(-expf(alog[hh]) * sp);
    }
  }
}

// ---------------------------------------------------------------------------
// Scan pass A: per (b,h,seg) local scan (h0=0). xbc is f16 now.
// ---------------------------------------------------------------------------
__global__ __launch_bounds__(64) void scanA_kernel(
    _Float16* __restrict__ xbc, const float* __restrict__ dtp,
    const float* __restrict__ dap, const float* __restrict__ Dv,
    float* __restrict__ Hseg, float* __restrict__ cumq)
{
  __shared__ float sbc[SEGLEN][32];
  __shared__ float sdt[SEGLEN], sda[SEGLEN];
  const int lane = threadIdx.x;
  const int seg = blockIdx.x & (NSEG - 1);
  const int bh = blockIdx.x >> 6;
  const int h = bh % NHEADS, b = bh / NHEADS;
  const float Dh = Dv[h];
  const int bl0 = b * L_SEQ + seg * SEGLEN;

  for (int i = lane; i < SEGLEN * 4; i += 64) {
    int t = i >> 2, q = (i & 3) << 3;
    f16x8 v = *(const f16x8*)&xbc[(size_t)(bl0 + t) * CONVD + D_INNER + q];
#pragma unroll
    for (int e = 0; e < 8; ++e) sbc[t][q + e] = (float)v[e];
  }
  sdt[lane] = dtp[(size_t)(bl0 + lane) * NHEADS + h];
  float myda = dap[(size_t)(bl0 + lane) * NHEADS + h];
  sda[lane] = myda;
  __syncthreads();

  float pp = myda;
#pragma unroll
  for (int off = 1; off < 64; off <<= 1) {
    float tv = __shfl_up(pp, off, 64);
    if (lane >= off) pp *= tv;
  }
  cumq[(size_t)bh * L_SEQ + seg * SEGLEN + lane] = pp;

  float hs[16];
#pragma unroll
  for (int n = 0; n < 16; ++n) hs[n] = 0.f;

  size_t xaddr = (size_t)bl0 * CONVD + h * HEADDIM + lane;
  float xv = (float)xbc[xaddr];
  for (int t = 0; t < SEGLEN; ++t) {
    float xn = (t < SEGLEN - 1) ? (float)xbc[xaddr + CONVD] : 0.f;
    float dav = sda[t];
    float coef = sdt[t] * xv;
    float y0 = 0.f, y1 = 0.f, y2 = 0.f, y3 = 0.f;
#pragma unroll
    for (int n = 0; n < 16; ++n) {
      float hv = fmaf(hs[n], dav, coef * sbc[t][n]);
      hs[n] = hv;
      float cvv = sbc[t][16 + n];
      if ((n & 3) == 0)      y0 = fmaf(hv, cvv, y0);
      else if ((n & 3) == 1) y1 = fmaf(hv, cvv, y1);
      else if ((n & 3) == 2) y2 = fmaf(hv, cvv, y2);
      else                   y3 = fmaf(hv, cvv, y3);
    }
    xbc[xaddr] = (_Float16)fmaf(Dh, xv, (y0 + y1) + (y2 + y3));
    xv = xn;
    xaddr += CONVD;
  }

  float* Hst = Hseg + ((size_t)bh * NSEG + seg) * 1024 + lane * 16;
#pragma unroll
  for (int n = 0; n < 16; n += 4)
    *(float4*)&Hst[n] = make_float4(hs[n], hs[n + 1], hs[n + 2], hs[n + 3]);
}

// ---------------------------------------------------------------------------
// Pass B: per (b,h), 1024 threads; thread owns one (p,n) element; all 64
// segment values loaded into registers (independent), then 64-step scan.
// Hseg slot becomes ENTRY state.
// ---------------------------------------------------------------------------
__global__ __launch_bounds__(1024) void scanB_kernel(
    float* __restrict__ Hseg, const float* __restrict__ cumq)
{
  const int bh = blockIdx.x;
  const int t = threadIdx.x;           // p*16+n
  __shared__ float sp[NSEG];
  if (t < NSEG) sp[t] = cumq[(size_t)bh * L_SEQ + t * SEGLEN + (SEGLEN - 1)];
  __syncthreads();
  float v[NSEG];
#pragma unroll
  for (int s = 0; s < NSEG; ++s)
    v[s] = Hseg[((size_t)bh * NSEG + s) * 1024 + t];
  float h = 0.f;
#pragma unroll
  for (int s = 0; s < NSEG; ++s) {
    Hseg[((size_t)bh * NSEG + s) * 1024 + t] = h;
    h = fmaf(sp[s], h, v[s]);
  }
}

// Pass C: y += cumprod * (C . h_entry)   (xbc f16)
__global__ __launch_bounds__(64) void scanC_kernel(
    _Float16* __restrict__ xbc, const float* __restrict__ Hseg,
    const float* __restrict__ cumq)
{
  const int seg = blockIdx.x & (NSEG - 1);
  if (seg == 0) return;
  __shared__ float sc[SEGLEN][16];
  __shared__ float scq[SEGLEN];
  const int lane = threadIdx.x;
  const int bh = blockIdx.x >> 6;
  const int h = bh % NHEADS, b = bh / NHEADS;
  const int bl0 = b * L_SEQ + seg * SEGLEN;
  const float* slot = Hseg + ((size_t)bh * NSEG + seg) * 1024 + lane * 16;
  float hin[16];
#pragma unroll
  for (int n = 0; n < 16; n += 4) {
    float4 v = *(const float4*)(slot + n);
    hin[n] = v.x; hin[n + 1] = v.y; hin[n + 2] = v.z; hin[n + 3] = v.w;
  }
  for (int i = lane; i < SEGLEN * 2; i += 64) {
    int t = i >> 1, q = (i & 1) << 3;
    f16x8 v = *(const f16x8*)&xbc[(size_t)(bl0 + t) * CONVD + D_INNER + D_STATE + q];
#pragma unroll
    for (int e = 0; e < 8; ++e) sc[t][q + e] = (float)v[e];
  }
  scq[lane] = cumq[(size_t)bh * L_SEQ + seg * SEGLEN + lane];
  __syncthreads();
  for (int t = 0; t < SEGLEN; ++t) {
    float dot = 0.f;
#pragma unroll
    for (int n = 0; n < 16; ++n) dot = fmaf(hin[n], sc[t][n], dot);
    size_t ad = (size_t)(bl0 + t) * CONVD + h * HEADDIM + lane;
    xbc[ad] = (_Float16)fmaf(scq[t], dot, (float)xbc[ad]);
  }
}

// ---------------------------------------------------------------------------
// y *= silu(z); RMS-norm over 1536; * norm_w; f16 result overwrites zx cols
// 0..1535 of the same row. y read from xbc (f16, stride 1568).
// ---------------------------------------------------------------------------
__global__ __launch_bounds__(256) void norm_kernel(
    const _Float16* __restrict__ y, _Float16* __restrict__ zx,
    const float* __restrict__ nw)
{
  const int row = blockIdx.x;
  const int tid = threadIdx.x;
  const _Float16* yr = y + (size_t)row * CONVD;
  _Float16* zr = zx + (size_t)row * ZXP;
  float v[6];
  float ss = 0.f;
#pragma unroll
  for (int jj = 0; jj < 6; ++jj) {
    int c = jj * 256 + tid;
    float yv = (float)yr[c];
    float zv = (float)zr[c];
    float sz = zv / (1.f + expf(-zv));
    float val = yv * sz;
    v[jj] = val;
    ss = fmaf(val, val, ss);
  }
#pragma unroll
  for (int off = 32; off > 0; off >>= 1) ss += __shfl_xor(ss, off, 64);
  __shared__ float red[4];
  if ((tid & 63) == 0) red[tid >> 6] = ss;
  __syncthreads();
  float tot = red[0] + red[1] + red[2] + red[3];
  float rs = rsqrtf(tot * (1.f / 1536.f) + 1e-5f);
#pragma unroll
  for (int jj = 0; jj < 6; ++jj) {
    int c = jj * 256 + tid;
    zr[c] = (_Float16)(v[jj] * rs * nw[c]);
  }
}

// ---------------------------------------------------------------------------
extern "C" void kernel_launch(void* const* d_in, const int* in_sizes, int n_in,
                              void* d_out, int out_size, void* d_ws, size_t ws_size,
                              hipStream_t stream)
{
  const float* x_in = (const float*)d_in[0];
  const int*   tids = (const int*)d_in[1];
  const float* ipw  = (const float*)d_in[2];
  const float* cw   = (const float*)d_in[3];
  const float* cb   = (const float*)d_in[4];
  const float* dtb  = (const float*)d_in[5];
  const float* alog = (const float*)d_in[6];
  const float* Dv   = (const float*)d_in[7];
  const float* nw   = (const float*)d_in[8];
  const float* opw  = (const float*)d_in[9];
  const float* hw   = (const float*)d_in[10];
  const float* hb   = (const float*)d_in[11];
  const float* how  = (const float*)d_in[12];
  const float* hob  = (const float*)d_in[13];
  float* out = (float*)d_out;

  // ---- workspace carve: f16 weights (upfront) + per-chunk activations ----
  char* p = (char*)d_ws;
  _Float16* ipw_b = (_Float16*)p; p += (size_t)14413824 * 2;  // 6*3128*768
  _Float16* opw_b = (_Float16*)p; p += (size_t)7077888 * 2;   // 6*768*1536
  _Float16* hw_b  = (_Float16*)p; p += (size_t)1179648 * 2;   // 2*768*768
  _Float16* how_b = (_Float16*)p; p += (size_t)786432 * 2;    // 2*512*768
  float*    hob_p = (float*)p;    p += (size_t)1024 * 4;
  const size_t used_w = (size_t)(p - (char*)d_ws);
  // per batch: zx 26.2MB + xbc(f16) 12.8MB + Hseg 6.3MB + dt/da/cumq 1.2MB + xbuf 6.3MB
  const size_t PB = 52822016;
  int nb = 4;
  while (nb > 1 && used_w + (size_t)nb * PB > ws_size) nb >>= 1;

  // ---- weight conversions (idempotent, every launch) ----
  cvt_kernel<<<8192, 256, 0, stream>>>(ipw, ipw_b, 14413824 / 4);
  cvt_kernel<<<6912, 256, 0, stream>>>(opw, opw_b, 7077888 / 4);
  cvt_kernel<<<1152, 256, 0, stream>>>(hw, hw_b, 1179648 / 4);
  pack_head_kernel<<<3072, 256, 0, stream>>>(how, hob, how_b, hob_p);

  for (int b0 = 0; b0 < BATCH; b0 += nb) {
    const int MT = nb * L_SEQ;
    _Float16* zx  = (_Float16*)p;
    _Float16* xbc = zx + (size_t)MT * ZXP;
    float* Hseg = (float*)(xbc + (size_t)MT * CONVD);
    float* dtp  = Hseg + (size_t)nb * NHEADS * NSEG * 1024;
    float* dap  = dtp + (size_t)MT * NHEADS;
    float* cumq = dap + (size_t)MT * NHEADS;
    _Float16* xbuf = (_Float16*)(cumq + (size_t)MT * NHEADS);
    _Float16* hbuf = zx;   // head hidden, dense [MT][768]; zx dead at head stage

    cvt_kernel<<<6144, 256, 0, stream>>>(x_in + (size_t)b0 * L_SEQ * DIMM,
                                         xbuf, (long)MT * DIMM / 4);

    for (int i = 0; i < 6; ++i) {
      gemm_mfma<0><<<dim3((D_IPROJ + 127) / 128, MT / 128), 256, 0, stream>>>(
          xbuf, DIMM, ipw_b + (size_t)i * D_IPROJ * DIMM, nullptr,
          zx, ZXP, 0, MT, D_IPROJ, DIMM, nullptr, 0);
      conv_dt_kernel<<<(MT * CGRP) / 256, 256, 0, stream>>>(
          zx, cw + (size_t)i * CONVD * 4, cb + i * CONVD, xbc,
          dtb + i * NHEADS, alog + i * NHEADS, dtp, dap);
      scanA_kernel<<<nb * NHEADS * NSEG, 64, 0, stream>>>(
          xbc, dtp, dap, Dv + i * NHEADS, Hseg, cumq);
      scanB_kernel<<<nb * NHEADS, 1024, 0, stream>>>(Hseg, cumq);
      scanC_kernel<<<nb * NHEADS * NSEG, 64, 0, stream>>>(xbc, Hseg, cumq);
      norm_kernel<<<MT, 256, 0, stream>>>(xbc, zx, nw + i * D_INNER);
      gemm_mfma<0><<<dim3(DIMM / 128, MT / 128), 256, 0, stream>>>(
          zx, ZXP, opw_b + (size_t)i * DIMM * D_INNER, nullptr,
          xbuf, DIMM, 0, MT, DIMM, D_INNER, nullptr, 0);
    }

    for (int t = 0; t < 2; ++t) {
      gemm_mfma<2><<<dim3(DIMM / 128, MT / 128), 256, 0, stream>>>(
          xbuf, DIMM, hw_b + (size_t)t * DIMM * DIMM, hb + t * DIMM,
          hbuf, DIMM, 0, MT, DIMM, DIMM, nullptr, 0);
      gemm_mfma<3><<<dim3(4, MT / 128), 256, 0, stream>>>(
          hbuf, DIMM, how_b + (size_t)t * 512 * DIMM, hob_p + t * 512,
          out + (size_t)t * 4 * 16384 * 128 + (size_t)b0 * L_SEQ * 128,
          128, (long)16384 * 128, MT, 512, DIMM,
          tids + (size_t)b0 * L_SEQ, t);
    }
  }
}

// Round 11
// 2145.229 us; speedup vs baseline: 4.1837x; 1.3968x over previous
//
#include <hip/hip_runtime.h>
#include <cstdint>
#include <cstddef>

#define L_SEQ   4096
#define BATCH   4
#define DIMM    768
#define D_INNER 1536
#define NHEADS  24
#define HEADDIM 64
#define D_STATE 16
#define CONVD   1568
#define D_IPROJ 3128
#define ZXP     3200     // padded zx row stride (6400B = 64B-aligned rows)
#define SEGLEN  64
#define NSEG    (L_SEQ / SEGLEN)   // 64

typedef _Float16 f16x8 __attribute__((ext_vector_type(8)));
typedef _Float16 f16x4 __attribute__((ext_vector_type(4)));
typedef float    f32x4 __attribute__((ext_vector_type(4)));

__device__ __forceinline__ void glds16(const _Float16* g, _Float16* l) {
  __builtin_amdgcn_global_load_lds(
      (__attribute__((address_space(1))) unsigned int*)g,
      (__attribute__((address_space(3))) unsigned int*)l, 16, 0, 0);
}

// ---------------------------------------------------------------------------
// f16 MFMA GEMM (unchanged from round 9): 128x128x64 tile, 4 waves,
// global_load_lds staging, XOR swizzle via pre-swizzled global source,
// XCD-band block swizzle, LDS-transpose epilogue.
// OM: 0 = f16 out (+ col<N guard), 2 = f16 out + f32 bias,
//     3 = f32 out + bias + sigmoid(q>0) + type-mask (head fusion; N=512)
// ---------------------------------------------------------------------------
template <int OM>
__global__ __launch_bounds__(256, 2) void gemm_mfma(
    const _Float16* __restrict__ A, int lda,
    const _Float16* __restrict__ W,
    const float* __restrict__ bias,
    void* __restrict__ Cv, long ldc, long extra,
    int M, int N, int K,
    const int* __restrict__ tidsp, int thead)
{
  __shared__ __align__(16) char smem[33792];
  _Float16* As = (_Float16*)smem;
  _Float16* Ws = (_Float16*)(smem + 16384);
  const int tid = threadIdx.x;
  const int lane = tid & 63, wid = tid >> 6;
  const int wr = wid >> 1, wc = wid & 1;

  const int nbx = gridDim.x, nby = gridDim.y;
  const int flat = blockIdx.y * nbx + blockIdx.x;
  const int xcd = flat & 7;
  const int bidx = flat >> 3;
  const int rpx = nby >> 3;
  const int rl = bidx % rpx;
  const int ct = bidx / rpx;
  const long m0 = (long)(xcd * rpx + rl) * 128;
  const int n0 = ct * 128;

  const int la = lane & 15, lg = lane >> 4;
  const int srow = lane >> 3, schunk = lane & 7;

  f32x4 acc[4][4] = {};

  for (int k0 = 0; k0 < K; k0 += 64) {
    __syncthreads();
#pragma unroll
    for (int p = 0; p < 4; ++p) {
      const int rg = (wid << 2) + p;
      const int row = (rg << 3) + srow;
      const int scn = schunk ^ (row & 7);
      glds16(A + (m0 + row) * (long)lda + k0 + scn * 8, As + rg * 512);
      int n = n0 + row; if (n >= N) n = N - 1;
      glds16(W + (long)n * K + k0 + scn * 8, Ws + rg * 512);
    }
    asm volatile("s_waitcnt vmcnt(0)" ::: "memory");
    __syncthreads();
#pragma unroll
    for (int ks = 0; ks < 2; ++ks) {
      const int cc = ks * 4 + lg;
      f16x8 af[4], bfr[4];
#pragma unroll
      for (int i = 0; i < 4; ++i) {
        int ra = wr * 64 + i * 16 + la;
        int rb = wc * 64 + i * 16 + la;
        af[i]  = *(const f16x8*)&As[ra * 64 + ((cc ^ (ra & 7)) << 3)];
        bfr[i] = *(const f16x8*)&Ws[rb * 64 + ((cc ^ (rb & 7)) << 3)];
      }
#pragma unroll
      for (int i = 0; i < 4; ++i)
#pragma unroll
        for (int j = 0; j < 4; ++j)
          acc[i][j] = __builtin_amdgcn_mfma_f32_16x16x32_f16(af[i], bfr[j], acc[i][j], 0, 0, 0);
    }
  }

  float* epi = (float*)smem;                    // [64][132]
#pragma unroll
  for (int ph = 0; ph < 2; ++ph) {
    __syncthreads();
    if (wr == ph) {
#pragma unroll
      for (int i = 0; i < 4; ++i)
#pragma unroll
        for (int j = 0; j < 4; ++j)
#pragma unroll
          for (int r = 0; r < 4; ++r)
            epi[(i * 16 + lg * 4 + r) * 132 + wc * 64 + j * 16 + la] = acc[i][j][r];
    }
    __syncthreads();
    if (OM == 3) {
      const int q = n0 >> 7;
      const int rr = tid >> 5;
      const int ch = tid & 31;
#pragma unroll
      for (int ps = 0; ps < 8; ++ps) {
        int lrow = ps * 8 + rr;
        long gr = m0 + ph * 64 + lrow;
        float keep = (tidsp[gr] == thead) ? 1.f : 0.f;
        float4 v = *(float4*)&epi[lrow * 132 + ch * 4];
        float o[4] = {v.x, v.y, v.z, v.w};
#pragma unroll
        for (int e = 0; e < 4; ++e) {
          float vv = o[e] + bias[n0 + ch * 4 + e];
          if (q != 0) vv = 1.f / (1.f + expf(-vv));
          o[e] = vv * keep;
        }
        *(float4*)((float*)Cv + (long)q * extra + gr * 128 + ch * 4) =
            make_float4(o[0], o[1], o[2], o[3]);
      }
    } else {
      const int rr = tid >> 4;
      const int ch = tid & 15;
      const int col = n0 + ch * 8;
      float b[8] = {0.f, 0.f, 0.f, 0.f, 0.f, 0.f, 0.f, 0.f};
      if (OM == 2 && col < N) {
#pragma unroll
        for (int e = 0; e < 8; ++e) b[e] = bias[col + e];
      }
#pragma unroll
      for (int ps = 0; ps < 4; ++ps) {
        int lrow = ps * 16 + rr;
        long gr = m0 + ph * 64 + lrow;
        if (col < N) {
          float4 v0 = *(float4*)&epi[lrow * 132 + ch * 8];
          float4 v1 = *(float4*)&epi[lrow * 132 + ch * 8 + 4];
          f16x8 o = {(_Float16)(v0.x + b[0]), (_Float16)(v0.y + b[1]),
                     (_Float16)(v0.z + b[2]), (_Float16)(v0.w + b[3]),
                     (_Float16)(v1.x + b[4]), (_Float16)(v1.y + b[5]),
                     (_Float16)(v1.z + b[6]), (_Float16)(v1.w + b[7])};
          *(f16x8*)((_Float16*)Cv + gr * ldc + col) = o;
        }
      }
    }
  }
}

// ---------------------------------------------------------------------------
__global__ __launch_bounds__(256) void cvt_kernel(
    const float* __restrict__ src, _Float16* __restrict__ dst, long n4)
{
  long i = (long)blockIdx.x * 256 + threadIdx.x;
  long stride = (long)gridDim.x * 256;
  for (; i < n4; i += stride) {
    float4 v = *(const float4*)(src + i * 4);
    f16x4 o = { (_Float16)v.x, (_Float16)v.y, (_Float16)v.z, (_Float16)v.w };
    *(f16x4*)(dst + i * 4) = o;
  }
}

__global__ __launch_bounds__(256) void pack_head_kernel(
    const float* __restrict__ how, const float* __restrict__ hob,
    _Float16* __restrict__ howb, float* __restrict__ hobp)
{
  const int wmap[4] = {0, 3, 1, 2};
  int idx = blockIdx.x * 256 + threadIdx.x;
  if (idx < 2 * 512 * 768) {
    int t = idx / (512 * 768);
    int rem = idx - t * 512 * 768;
    int q = rem / (128 * 768);
    int rem2 = rem - q * 128 * 768;
    howb[idx] = (_Float16)how[((size_t)(t * 4 + wmap[q])) * 128 * 768 + rem2];
  }
  if (idx < 1024) {
    int t = idx >> 9, rem = idx & 511;
    int q = rem >> 7, pp = rem & 127;
    hobp[idx] = hob[(t * 4 + wmap[q]) * 128 + pp];
  }
}

// ---------------------------------------------------------------------------
// Fused scan front: conv(4)+silu for this block's 64 x-channels and the 32
// B/C channels (staged with 3-row halo from zx), dt/dA (one per lane), local
// SSM scan (h0=0). Writes y -> ybuf (dense 1536), conv'ed B/C -> bcbuf,
// local exit state -> Hseg, inclusive cumprod(dA) -> cumq.
// ---------------------------------------------------------------------------
__global__ __launch_bounds__(64) void scanA_kernel(
    const _Float16* __restrict__ zx, const float* __restrict__ cw,
    const float* __restrict__ cb, const float* __restrict__ dtb,
    const float* __restrict__ alog, const float* __restrict__ Dv,
    _Float16* __restrict__ ybuf, _Float16* __restrict__ bcbuf,
    float* __restrict__ Hseg, float* __restrict__ cumq)
{
  __shared__ _Float16 sxr[67][64];
  __shared__ _Float16 sbcr[67][32];
  __shared__ float sbc[SEGLEN][32];
  __shared__ float sdt[SEGLEN], sda[SEGLEN];
  const int lane = threadIdx.x;
  const int seg = blockIdx.x & (NSEG - 1);
  const int bh = blockIdx.x >> 6;
  const int h = bh % NHEADS, b = bh / NHEADS;
  const int bl0 = b * L_SEQ + seg * SEGLEN;

  // stage x channels (64) with halo: rows bl0-3 .. bl0+63
  for (int i = lane; i < 67 * 8; i += 64) {
    int r = i >> 3, q = (i & 7) << 3;
    f16x8 v = {};
    if (seg > 0 || r >= 3)
      v = *(const f16x8*)&zx[(size_t)(bl0 - 3 + r) * ZXP + D_INNER + h * HEADDIM + q];
    *(f16x8*)&sxr[r][q] = v;
  }
  // stage B/C channels (32) with halo
  for (int i = lane; i < 67 * 4; i += 64) {
    int r = i >> 2, q = (i & 3) << 3;
    f16x8 v = {};
    if (seg > 0 || r >= 3)
      v = *(const f16x8*)&zx[(size_t)(bl0 - 3 + r) * ZXP + 2 * D_INNER + q];
    *(f16x8*)&sbcr[r][q] = v;
  }
  // dt/dA for own row; prefix product for cumq
  {
    float raw = (float)zx[(size_t)(bl0 + lane) * ZXP + (D_INNER + CONVD) + h] + dtb[h];
    float sp = (raw > 20.f) ? raw : log1pf(expf(raw));
    sdt[lane] = sp;
    float da = expf(-expf(alog[h]) * sp);
    sda[lane] = da;
    float pp = da;
#pragma unroll
    for (int off = 1; off < 64; off <<= 1) {
      float tv = __shfl_up(pp, off, 64);
      if (lane >= off) pp *= tv;
    }
    cumq[(size_t)bh * L_SEQ + seg * SEGLEN + lane] = pp;
  }
  __syncthreads();

  // conv+silu for B/C -> sbc (f32) and bcbuf (f16)
  for (int i = lane; i < SEGLEN * 32; i += 64) {
    int t = i >> 5, c = i & 31;
    float acc = cb[D_INNER + c];
#pragma unroll
    for (int k = 0; k < 4; ++k)
      acc = fmaf(cw[(D_INNER + c) * 4 + k], (float)sbcr[t + k][c], acc);
    float s = acc / (1.f + expf(-acc));
    sbc[t][c] = s;
    bcbuf[(size_t)(bl0 + t) * 32 + c] = (_Float16)s;
  }

  const int xc = h * HEADDIM + lane;
  const float cwx0 = cw[xc * 4 + 0], cwx1 = cw[xc * 4 + 1];
  const float cwx2 = cw[xc * 4 + 2], cwx3 = cw[xc * 4 + 3];
  const float cbx = cb[xc];
  const float Dh = Dv[h];
  __syncthreads();

  float hs[16];
#pragma unroll
  for (int n = 0; n < 16; ++n) hs[n] = 0.f;

  for (int t = 0; t < SEGLEN; ++t) {
    float xa = cbx;
    xa = fmaf(cwx0, (float)sxr[t + 0][lane], xa);
    xa = fmaf(cwx1, (float)sxr[t + 1][lane], xa);
    xa = fmaf(cwx2, (float)sxr[t + 2][lane], xa);
    xa = fmaf(cwx3, (float)sxr[t + 3][lane], xa);
    float xv = xa / (1.f + expf(-xa));
    float dav = sda[t];
    float coef = sdt[t] * xv;
    float y0 = 0.f, y1 = 0.f, y2 = 0.f, y3 = 0.f;
#pragma unroll
    for (int n = 0; n < 16; ++n) {
      float hv = fmaf(hs[n], dav, coef * sbc[t][n]);
      hs[n] = hv;
      float cvv = sbc[t][16 + n];
      if ((n & 3) == 0)      y0 = fmaf(hv, cvv, y0);
      else if ((n & 3) == 1) y1 = fmaf(hv, cvv, y1);
      else if ((n & 3) == 2) y2 = fmaf(hv, cvv, y2);
      else                   y3 = fmaf(hv, cvv, y3);
    }
    ybuf[(size_t)(bl0 + t) * D_INNER + h * HEADDIM + lane] =
        (_Float16)fmaf(Dh, xv, (y0 + y1) + (y2 + y3));
  }

  float* Hst = Hseg + ((size_t)bh * NSEG + seg) * 1024 + lane * 16;
#pragma unroll
  for (int n = 0; n < 16; n += 4)
    *(float4*)&Hst[n] = make_float4(hs[n], hs[n + 1], hs[n + 2], hs[n + 3]);
}

// ---------------------------------------------------------------------------
// Pass B: per (b,h), 1024 threads; thread owns one (p,n); 64-step scan in regs.
// ---------------------------------------------------------------------------
__global__ __launch_bounds__(1024) void scanB_kernel(
    float* __restrict__ Hseg, const float* __restrict__ cumq)
{
  const int bh = blockIdx.x;
  const int t = threadIdx.x;
  __shared__ float sp[NSEG];
  if (t < NSEG) sp[t] = cumq[(size_t)bh * L_SEQ + t * SEGLEN + (SEGLEN - 1)];
  __syncthreads();
  float v[NSEG];
#pragma unroll
  for (int s = 0; s < NSEG; ++s)
    v[s] = Hseg[((size_t)bh * NSEG + s) * 1024 + t];
  float h = 0.f;
#pragma unroll
  for (int s = 0; s < NSEG; ++s) {
    Hseg[((size_t)bh * NSEG + s) * 1024 + t] = h;
    h = fmaf(sp[s], h, v[s]);
  }
}

// Pass C: y += cumprod * (C . h_entry); C from bcbuf, y in ybuf.
__global__ __launch_bounds__(64) void scanC_kernel(
    _Float16* __restrict__ ybuf, const _Float16* __restrict__ bcbuf,
    const float* __restrict__ Hseg, const float* __restrict__ cumq)
{
  const int seg = blockIdx.x & (NSEG - 1);
  if (seg == 0) return;
  __shared__ float sc[SEGLEN][16];
  __shared__ float scq[SEGLEN];
  const int lane = threadIdx.x;
  const int bh = blockIdx.x >> 6;
  const int h = bh % NHEADS, b = bh / NHEADS;
  const int bl0 = b * L_SEQ + seg * SEGLEN;
  const float* slot = Hseg + ((size_t)bh * NSEG + seg) * 1024 + lane * 16;
  float hin[16];
#pragma unroll
  for (int n = 0; n < 16; n += 4) {
    float4 v = *(const float4*)(slot + n);
    hin[n] = v.x; hin[n + 1] = v.y; hin[n + 2] = v.z; hin[n + 3] = v.w;
  }
  for (int i = lane; i < SEGLEN * 2; i += 64) {
    int t = i >> 1, q = (i & 1) << 3;
    f16x8 v = *(const f16x8*)&bcbuf[(size_t)(bl0 + t) * 32 + D_STATE + q];
#pragma unroll
    for (int e = 0; e < 8; ++e) sc[t][q + e] = (float)v[e];
  }
  scq[lane] = cumq[(size_t)bh * L_SEQ + seg * SEGLEN + lane];
  __syncthreads();
  for (int t = 0; t < SEGLEN; ++t) {
    float dot = 0.f;
#pragma unroll
    for (int n = 0; n < 16; ++n) dot = fmaf(hin[n], sc[t][n], dot);
    size_t ad = (size_t)(bl0 + t) * D_INNER + h * HEADDIM + lane;
    ybuf[ad] = (_Float16)fmaf(scq[t], dot, (float)ybuf[ad]);
  }
}

// ---------------------------------------------------------------------------
// y *= silu(z); RMS-norm over 1536; * norm_w; f16 result overwrites zx cols
// 0..1535 of the same row. y read from dense ybuf.
// ---------------------------------------------------------------------------
__global__ __launch_bounds__(256) void norm_kernel(
    const _Float16* __restrict__ y, _Float16* __restrict__ zx,
    const float* __restrict__ nw)
{
  const int row = blockIdx.x;
  const int tid = threadIdx.x;
  const _Float16* yr = y + (size_t)row * D_INNER;
  _Float16* zr = zx + (size_t)row * ZXP;
  float v[6];
  float ss = 0.f;
#pragma unroll
  for (int jj = 0; jj < 6; ++jj) {
    int c = jj * 256 + tid;
    float yv = (float)yr[c];
    float zv = (float)zr[c];
    float sz = zv / (1.f + expf(-zv));
    float val = yv * sz;
    v[jj] = val;
    ss = fmaf(val, val, ss);
  }
#pragma unroll
  for (int off = 32; off > 0; off >>= 1) ss += __shfl_xor(ss, off, 64);
  __shared__ float red[4];
  if ((tid & 63) == 0) red[tid >> 6] = ss;
  __syncthreads();
  float tot = red[0] + red[1] + red[2] + red[3];
  float rs = rsqrtf(tot * (1.f / 1536.f) + 1e-5f);
#pragma unroll
  for (int jj = 0; jj < 6; ++jj) {
    int c = jj * 256 + tid;
    zr[c] = (_Float16)(v[jj] * rs * nw[c]);
  }
}

// ---------------------------------------------------------------------------
extern "C" void kernel_launch(void* const* d_in, const int* in_sizes, int n_in,
                              void* d_out, int out_size, void* d_ws, size_t ws_size,
                              hipStream_t stream)
{
  const float* x_in = (const float*)d_in[0];
  const int*   tids = (const int*)d_in[1];
  const float* ipw  = (const float*)d_in[2];
  const float* cw   = (const float*)d_in[3];
  const float* cb   = (const float*)d_in[4];
  const float* dtb  = (const float*)d_in[5];
  const float* alog = (const float*)d_in[6];
  const float* Dv   = (const float*)d_in[7];
  const float* nw   = (const float*)d_in[8];
  const float* opw  = (const float*)d_in[9];
  const float* hw   = (const float*)d_in[10];
  const float* hb   = (const float*)d_in[11];
  const float* how  = (const float*)d_in[12];
  const float* hob  = (const float*)d_in[13];
  float* out = (float*)d_out;

  // ---- workspace carve: f16 weights (upfront) + per-chunk activations ----
  char* p = (char*)d_ws;
  _Float16* ipw_b = (_Float16*)p; p += (size_t)14413824 * 2;  // 6*3128*768
  _Float16* opw_b = (_Float16*)p; p += (size_t)7077888 * 2;   // 6*768*1536
  _Float16* hw_b  = (_Float16*)p; p += (size_t)1179648 * 2;   // 2*768*768
  _Float16* how_b = (_Float16*)p; p += (size_t)786432 * 2;    // 2*512*768
  float*    hob_p = (float*)p;    p += (size_t)1024 * 4;
  const size_t used_w = (size_t)(p - (char*)d_ws);
  // per batch: zx 26.2MB + ybuf 12.6MB + bcbuf 0.26MB + Hseg 6.3MB
  //          + cumq 0.39MB + xbuf 6.3MB  = ~52.0MB
  const size_t PB = 54528000;
  int nb = 4;
  while (nb > 1 && used_w + (size_t)nb * PB > ws_size) nb >>= 1;

  cvt_kernel<<<8192, 256, 0, stream>>>(ipw, ipw_b, 14413824 / 4);
  cvt_kernel<<<6912, 256, 0, stream>>>(opw, opw_b, 7077888 / 4);
  cvt_kernel<<<1152, 256, 0, stream>>>(hw, hw_b, 1179648 / 4);
  pack_head_kernel<<<3072, 256, 0, stream>>>(how, hob, how_b, hob_p);

  for (int b0 = 0; b0 < BATCH; b0 += nb) {
    const int MT = nb * L_SEQ;
    _Float16* zx    = (_Float16*)p;
    _Float16* ybuf  = zx + (size_t)MT * ZXP;
    _Float16* bcbuf = ybuf + (size_t)MT * D_INNER;
    float*    Hseg  = (float*)(bcbuf + (size_t)MT * 32);
    float*    cumq  = Hseg + (size_t)nb * NHEADS * NSEG * 1024;
    _Float16* xbuf  = (_Float16*)(cumq + (size_t)MT * NHEADS);
    _Float16* hbuf  = zx;   // head hidden; zx dead at head stage

    cvt_kernel<<<6144, 256, 0, stream>>>(x_in + (size_t)b0 * L_SEQ * DIMM,
                                         xbuf, (long)MT * DIMM / 4);

    for (int i = 0; i < 6; ++i) {
      gemm_mfma<0><<<dim3((D_IPROJ + 127) / 128, MT / 128), 256, 0, stream>>>(
          xbuf, DIMM, ipw_b + (size_t)i * D_IPROJ * DIMM, nullptr,
          zx, ZXP, 0, MT, D_IPROJ, DIMM, nullptr, 0);
      scanA_kernel<<<nb * NHEADS * NSEG, 64, 0, stream>>>(
          zx, cw + (size_t)i * CONVD * 4, cb + i * CONVD,
          dtb + i * NHEADS, alog + i * NHEADS, Dv + i * NHEADS,
          ybuf, bcbuf, Hseg, cumq);
      scanB_kernel<<<nb * NHEADS, 1024, 0, stream>>>(Hseg, cumq);
      scanC_kernel<<<nb * NHEADS * NSEG, 64, 0, stream>>>(ybuf, bcbuf, Hseg, cumq);
      norm_kernel<<<MT, 256, 0, stream>>>(ybuf, zx, nw + i * D_INNER);
      gemm_mfma<0><<<dim3(DIMM / 128, MT / 128), 256, 0, stream>>>(
          zx, ZXP, opw_b + (size_t)i * DIMM * D_INNER, nullptr,
          xbuf, DIMM, 0, MT, DIMM, D_INNER, nullptr, 0);
    }

    for (int t = 0; t < 2; ++t) {
      gemm_mfma<2><<<dim3(DIMM / 128, MT / 128), 256, 0, stream>>>(
          xbuf, DIMM, hw_b + (size_t)t * DIMM * DIMM, hb + t * DIMM,
          hbuf, DIMM, 0, MT, DIMM, DIMM, nullptr, 0);
      gemm_mfma<3><<<dim3(4, MT / 128), 256, 0, stream>>>(
          hbuf, DIMM, how_b + (size_t)t * 512 * DIMM, hob_p + t * 512,
          out + (size_t)t * 4 * 16384 * 128 + (size_t)b0 * L_SEQ * 128,
          128, (long)16384 * 128, MT, 512, DIMM,
          tids + (size_t)b0 * L_SEQ, t);
    }
  }
}

// Round 12
// 2089.779 us; speedup vs baseline: 4.2947x; 1.0265x over previous
//
#include <hip/hip_runtime.h>
#include <cstdint>
#include <cstddef>

#define L_SEQ   4096
#define BATCH   4
#define DIMM    768
#define D_INNER 1536
#define NHEADS  24
#define HEADDIM 64
#define D_STATE 16
#define CONVD   1568
#define D_IPROJ 3128
#define ZXP     3200     // padded zx row stride (6400B = 64B-aligned rows)
#define SEGLEN  64
#define NSEG    (L_SEQ / SEGLEN)   // 64

typedef _Float16 f16x8 __attribute__((ext_vector_type(8)));
typedef _Float16 f16x4 __attribute__((ext_vector_type(4)));
typedef float    f32x4 __attribute__((ext_vector_type(4)));

__device__ __forceinline__ void glds16(const _Float16* g, _Float16* l) {
  __builtin_amdgcn_global_load_lds(
      (__attribute__((address_space(1))) unsigned int*)g,
      (__attribute__((address_space(3))) unsigned int*)l, 16, 0, 0);
}

// ---------------------------------------------------------------------------
// f16 MFMA GEMM (unchanged): 128x128x64 tile, 4 waves, global_load_lds
// staging, XOR swizzle via pre-swizzled global source, XCD-band swizzle,
// LDS-transpose epilogue.
// OM: 0 = f16 out (+ col<N guard), 2 = f16 out + f32 bias,
//     3 = f32 out + bias + sigmoid(q>0) + type-mask (head fusion; N=512)
// ---------------------------------------------------------------------------
template <int OM>
__global__ __launch_bounds__(256, 2) void gemm_mfma(
    const _Float16* __restrict__ A, int lda,
    const _Float16* __restrict__ W,
    const float* __restrict__ bias,
    void* __restrict__ Cv, long ldc, long extra,
    int M, int N, int K,
    const int* __restrict__ tidsp, int thead)
{
  __shared__ __align__(16) char smem[33792];
  _Float16* As = (_Float16*)smem;
  _Float16* Ws = (_Float16*)(smem + 16384);
  const int tid = threadIdx.x;
  const int lane = tid & 63, wid = tid >> 6;
  const int wr = wid >> 1, wc = wid & 1;

  const int nbx = gridDim.x, nby = gridDim.y;
  const int flat = blockIdx.y * nbx + blockIdx.x;
  const int xcd = flat & 7;
  const int bidx = flat >> 3;
  const int rpx = nby >> 3;
  const int rl = bidx % rpx;
  const int ct = bidx / rpx;
  const long m0 = (long)(xcd * rpx + rl) * 128;
  const int n0 = ct * 128;

  const int la = lane & 15, lg = lane >> 4;
  const int srow = lane >> 3, schunk = lane & 7;

  f32x4 acc[4][4] = {};

  for (int k0 = 0; k0 < K; k0 += 64) {
    __syncthreads();
#pragma unroll
    for (int p = 0; p < 4; ++p) {
      const int rg = (wid << 2) + p;
      const int row = (rg << 3) + srow;
      const int scn = schunk ^ (row & 7);
      glds16(A + (m0 + row) * (long)lda + k0 + scn * 8, As + rg * 512);
      int n = n0 + row; if (n >= N) n = N - 1;
      glds16(W + (long)n * K + k0 + scn * 8, Ws + rg * 512);
    }
    asm volatile("s_waitcnt vmcnt(0)" ::: "memory");
    __syncthreads();
#pragma unroll
    for (int ks = 0; ks < 2; ++ks) {
      const int cc = ks * 4 + lg;
      f16x8 af[4], bfr[4];
#pragma unroll
      for (int i = 0; i < 4; ++i) {
        int ra = wr * 64 + i * 16 + la;
        int rb = wc * 64 + i * 16 + la;
        af[i]  = *(const f16x8*)&As[ra * 64 + ((cc ^ (ra & 7)) << 3)];
        bfr[i] = *(const f16x8*)&Ws[rb * 64 + ((cc ^ (rb & 7)) << 3)];
      }
#pragma unroll
      for (int i = 0; i < 4; ++i)
#pragma unroll
        for (int j = 0; j < 4; ++j)
          acc[i][j] = __builtin_amdgcn_mfma_f32_16x16x32_f16(af[i], bfr[j], acc[i][j], 0, 0, 0);
    }
  }

  float* epi = (float*)smem;                    // [64][132]
#pragma unroll
  for (int ph = 0; ph < 2; ++ph) {
    __syncthreads();
    if (wr == ph) {
#pragma unroll
      for (int i = 0; i < 4; ++i)
#pragma unroll
        for (int j = 0; j < 4; ++j)
#pragma unroll
          for (int r = 0; r < 4; ++r)
            epi[(i * 16 + lg * 4 + r) * 132 + wc * 64 + j * 16 + la] = acc[i][j][r];
    }
    __syncthreads();
    if (OM == 3) {
      const int q = n0 >> 7;
      const int rr = tid >> 5;
      const int ch = tid & 31;
#pragma unroll
      for (int ps = 0; ps < 8; ++ps) {
        int lrow = ps * 8 + rr;
        long gr = m0 + ph * 64 + lrow;
        float keep = (tidsp[gr] == thead) ? 1.f : 0.f;
        float4 v = *(float4*)&epi[lrow * 132 + ch * 4];
        float o[4] = {v.x, v.y, v.z, v.w};
#pragma unroll
        for (int e = 0; e < 4; ++e) {
          float vv = o[e] + bias[n0 + ch * 4 + e];
          if (q != 0) vv = 1.f / (1.f + expf(-vv));
          o[e] = vv * keep;
        }
        *(float4*)((float*)Cv + (long)q * extra + gr * 128 + ch * 4) =
            make_float4(o[0], o[1], o[2], o[3]);
      }
    } else {
      const int rr = tid >> 4;
      const int ch = tid & 15;
      const int col = n0 + ch * 8;
      float b[8] = {0.f, 0.f, 0.f, 0.f, 0.f, 0.f, 0.f, 0.f};
      if (OM == 2 && col < N) {
#pragma unroll
        for (int e = 0; e < 8; ++e) b[e] = bias[col + e];
      }
#pragma unroll
      for (int ps = 0; ps < 4; ++ps) {
        int lrow = ps * 16 + rr;
        long gr = m0 + ph * 64 + lrow;
        if (col < N) {
          float4 v0 = *(float4*)&epi[lrow * 132 + ch * 8];
          float4 v1 = *(float4*)&epi[lrow * 132 + ch * 8 + 4];
          f16x8 o = {(_Float16)(v0.x + b[0]), (_Float16)(v0.y + b[1]),
                     (_Float16)(v0.z + b[2]), (_Float16)(v0.w + b[3]),
                     (_Float16)(v1.x + b[4]), (_Float16)(v1.y + b[5]),
                     (_Float16)(v1.z + b[6]), (_Float16)(v1.w + b[7])};
          *(f16x8*)((_Float16*)Cv + gr * ldc + col) = o;
        }
      }
    }
  }
}

// ---------------------------------------------------------------------------
__global__ __launch_bounds__(256) void cvt_kernel(
    const float* __restrict__ src, _Float16* __restrict__ dst, long n4)
{
  long i = (long)blockIdx.x * 256 + threadIdx.x;
  long stride = (long)gridDim.x * 256;
  for (; i < n4; i += stride) {
    float4 v = *(const float4*)(src + i * 4);
    f16x4 o = { (_Float16)v.x, (_Float16)v.y, (_Float16)v.z, (_Float16)v.w };
    *(f16x4*)(dst + i * 4) = o;
  }
}

__global__ __launch_bounds__(256) void pack_head_kernel(
    const float* __restrict__ how, const float* __restrict__ hob,
    _Float16* __restrict__ howb, float* __restrict__ hobp)
{
  const int wmap[4] = {0, 3, 1, 2};
  int idx = blockIdx.x * 256 + threadIdx.x;
  if (idx < 2 * 512 * 768) {
    int t = idx / (512 * 768);
    int rem = idx - t * 512 * 768;
    int q = rem / (128 * 768);
    int rem2 = rem - q * 128 * 768;
    howb[idx] = (_Float16)how[((size_t)(t * 4 + wmap[q])) * 128 * 768 + rem2];
  }
  if (idx < 1024) {
    int t = idx >> 9, rem = idx & 511;
    int q = rem >> 7, pp = rem & 127;
    hobp[idx] = hob[(t * 4 + wmap[q]) * 128 + pp];
  }
}

// ---------------------------------------------------------------------------
// Fused scan front (low-LDS version): B/C staged+conv'ed in LDS (f16);
// x conv via rolling register window from coalesced global reads; dt/dA per
// lane; local scan. LDS ~9KB -> high occupancy.
// ---------------------------------------------------------------------------
__global__ __launch_bounds__(64) void scanA_kernel(
    const _Float16* __restrict__ zx, const float* __restrict__ cw,
    const float* __restrict__ cb, const float* __restrict__ dtb,
    const float* __restrict__ alog, const float* __restrict__ Dv,
    _Float16* __restrict__ ybuf, _Float16* __restrict__ bcbuf,
    float* __restrict__ Hseg, float* __restrict__ cumq)
{
  __shared__ _Float16 sbcr[67][32];     // raw B/C halo (4288 B)
  __shared__ _Float16 sbc[SEGLEN][32];  // conv'ed B/C  (4096 B)
  __shared__ float sdt[SEGLEN], sda[SEGLEN];
  const int lane = threadIdx.x;
  const int seg = blockIdx.x & (NSEG - 1);
  const int bh = blockIdx.x >> 6;
  const int h = bh % NHEADS, b = bh / NHEADS;
  const int bl0 = b * L_SEQ + seg * SEGLEN;

  // stage raw B/C (32 ch) with 3-row halo
  for (int i = lane; i < 67 * 4; i += 64) {
    int r = i >> 2, q = (i & 3) << 3;
    f16x8 v = {};
    if (seg > 0 || r >= 3)
      v = *(const f16x8*)&zx[(size_t)(bl0 - 3 + r) * ZXP + 2 * D_INNER + q];
    *(f16x8*)&sbcr[r][q] = v;
  }
  // dt/dA for own row; prefix product for cumq
  {
    float raw = (float)zx[(size_t)(bl0 + lane) * ZXP + (D_INNER + CONVD) + h] + dtb[h];
    float sp = (raw > 20.f) ? raw : log1pf(expf(raw));
    sdt[lane] = sp;
    float da = expf(-expf(alog[h]) * sp);
    sda[lane] = da;
    float pp = da;
#pragma unroll
    for (int off = 1; off < 64; off <<= 1) {
      float tv = __shfl_up(pp, off, 64);
      if (lane >= off) pp *= tv;
    }
    cumq[(size_t)bh * L_SEQ + seg * SEGLEN + lane] = pp;
  }
  __syncthreads();

  // conv+silu for B/C -> sbc (f16) and bcbuf (f16)
  for (int i = lane; i < SEGLEN * 32; i += 64) {
    int t = i >> 5, c = i & 31;
    float acc = cb[D_INNER + c];
#pragma unroll
    for (int k = 0; k < 4; ++k)
      acc = fmaf(cw[(D_INNER + c) * 4 + k], (float)sbcr[t + k][c], acc);
    float s = acc / (1.f + expf(-acc));
    _Float16 sh = (_Float16)s;
    sbc[t][c] = sh;
    bcbuf[(size_t)(bl0 + t) * 32 + c] = sh;
  }

  // x: rolling register window, direct coalesced global reads
  const int xc = h * HEADDIM + lane;
  const _Float16* xg = zx + (size_t)bl0 * ZXP + D_INNER + xc;
  const float cwx0 = cw[xc * 4 + 0], cwx1 = cw[xc * 4 + 1];
  const float cwx2 = cw[xc * 4 + 2], cwx3 = cw[xc * 4 + 3];
  const float cbx = cb[xc];
  const float Dh = Dv[h];
  float xw0 = 0.f, xw1 = 0.f, xw2 = 0.f;
  if (seg > 0) {
    xw0 = (float)xg[-3 * (long)ZXP];
    xw1 = (float)xg[-2 * (long)ZXP];
    xw2 = (float)xg[-1 * (long)ZXP];
  }
  float xcur = (float)xg[0];
  __syncthreads();

  float hs[16];
#pragma unroll
  for (int n = 0; n < 16; ++n) hs[n] = 0.f;

  _Float16* yg = ybuf + (size_t)bl0 * D_INNER + xc;
  for (int t = 0; t < SEGLEN; ++t) {
    float xnext = (t < SEGLEN - 1) ? (float)xg[(size_t)(t + 1) * ZXP] : 0.f;
    float xa = cbx;
    xa = fmaf(cwx0, xw0, xa);
    xa = fmaf(cwx1, xw1, xa);
    xa = fmaf(cwx2, xw2, xa);
    xa = fmaf(cwx3, xcur, xa);
    float xv = xa / (1.f + expf(-xa));
    float dav = sda[t];
    float coef = sdt[t] * xv;
    f16x8 bb0 = *(const f16x8*)&sbc[t][0];
    f16x8 bb1 = *(const f16x8*)&sbc[t][8];
    f16x8 cc0 = *(const f16x8*)&sbc[t][16];
    f16x8 cc1 = *(const f16x8*)&sbc[t][24];
    float y0 = 0.f, y1 = 0.f, y2 = 0.f, y3 = 0.f;
#pragma unroll
    for (int n = 0; n < 8; ++n) {
      float hv = fmaf(hs[n], dav, coef * (float)bb0[n]);
      hs[n] = hv;
      float cvv = (float)cc0[n];
      if ((n & 3) == 0)      y0 = fmaf(hv, cvv, y0);
      else if ((n & 3) == 1) y1 = fmaf(hv, cvv, y1);
      else if ((n & 3) == 2) y2 = fmaf(hv, cvv, y2);
      else                   y3 = fmaf(hv, cvv, y3);
    }
#pragma unroll
    for (int n = 0; n < 8; ++n) {
      float hv = fmaf(hs[8 + n], dav, coef * (float)bb1[n]);
      hs[8 + n] = hv;
      float cvv = (float)cc1[n];
      if ((n & 3) == 0)      y0 = fmaf(hv, cvv, y0);
      else if ((n & 3) == 1) y1 = fmaf(hv, cvv, y1);
      else if ((n & 3) == 2) y2 = fmaf(hv, cvv, y2);
      else                   y3 = fmaf(hv, cvv, y3);
    }
    yg[(size_t)t * D_INNER] = (_Float16)fmaf(Dh, xv, (y0 + y1) + (y2 + y3));
    xw0 = xw1; xw1 = xw2; xw2 = xcur; xcur = xnext;
  }

  float* Hst = Hseg + ((size_t)bh * NSEG + seg) * 1024 + lane * 16;
#pragma unroll
  for (int n = 0; n < 16; n += 4)
    *(float4*)&Hst[n] = make_float4(hs[n], hs[n + 1], hs[n + 2], hs[n + 3]);
}

// ---------------------------------------------------------------------------
// Pass B: per (b,h), 1024 threads; thread owns one (p,n); 64-step scan in regs.
// ---------------------------------------------------------------------------
__global__ __launch_bounds__(1024) void scanB_kernel(
    float* __restrict__ Hseg, const float* __restrict__ cumq)
{
  const int bh = blockIdx.x;
  const int t = threadIdx.x;
  __shared__ float sp[NSEG];
  if (t < NSEG) sp[t] = cumq[(size_t)bh * L_SEQ + t * SEGLEN + (SEGLEN - 1)];
  __syncthreads();
  float v[NSEG];
#pragma unroll
  for (int s = 0; s < NSEG; ++s)
    v[s] = Hseg[((size_t)bh * NSEG + s) * 1024 + t];
  float h = 0.f;
#pragma unroll
  for (int s = 0; s < NSEG; ++s) {
    Hseg[((size_t)bh * NSEG + s) * 1024 + t] = h;
    h = fmaf(sp[s], h, v[s]);
  }
}

// Pass C: y += cumprod * (C . h_entry); C from bcbuf, y in ybuf.
__global__ __launch_bounds__(64) void scanC_kernel(
    _Float16* __restrict__ ybuf, const _Float16* __restrict__ bcbuf,
    const float* __restrict__ Hseg, const float* __restrict__ cumq)
{
  const int seg = blockIdx.x & (NSEG - 1);
  if (seg == 0) return;
  __shared__ float sc[SEGLEN][16];
  __shared__ float scq[SEGLEN];
  const int lane = threadIdx.x;
  const int bh = blockIdx.x >> 6;
  const int h = bh % NHEADS, b = bh / NHEADS;
  const int bl0 = b * L_SEQ + seg * SEGLEN;
  const float* slot = Hseg + ((size_t)bh * NSEG + seg) * 1024 + lane * 16;
  float hin[16];
#pragma unroll
  for (int n = 0; n < 16; n += 4) {
    float4 v = *(const float4*)(slot + n);
    hin[n] = v.x; hin[n + 1] = v.y; hin[n + 2] = v.z; hin[n + 3] = v.w;
  }
  for (int i = lane; i < SEGLEN * 2; i += 64) {
    int t = i >> 1, q = (i & 1) << 3;
    f16x8 v = *(const f16x8*)&bcbuf[(size_t)(bl0 + t) * 32 + D_STATE + q];
#pragma unroll
    for (int e = 0; e < 8; ++e) sc[t][q + e] = (float)v[e];
  }
  scq[lane] = cumq[(size_t)bh * L_SEQ + seg * SEGLEN + lane];
  __syncthreads();
  for (int t = 0; t < SEGLEN; ++t) {
    float dot = 0.f;
#pragma unroll
    for (int n = 0; n < 16; ++n) dot = fmaf(hin[n], sc[t][n], dot);
    size_t ad = (size_t)(bl0 + t) * D_INNER + h * HEADDIM + lane;
    ybuf[ad] = (_Float16)fmaf(scq[t], dot, (float)ybuf[ad]);
  }
}

// ---------------------------------------------------------------------------
__global__ __launch_bounds__(256) void norm_kernel(
    const _Float16* __restrict__ y, _Float16* __restrict__ zx,
    const float* __restrict__ nw)
{
  const int row = blockIdx.x;
  const int tid = threadIdx.x;
  const _Float16* yr = y + (size_t)row * D_INNER;
  _Float16* zr = zx + (size_t)row * ZXP;
  float v[6];
  float ss = 0.f;
#pragma unroll
  for (int jj = 0; jj < 6; ++jj) {
    int c = jj * 256 + tid;
    float yv = (float)yr[c];
    float zv = (float)zr[c];
    float sz = zv / (1.f + expf(-zv));
    float val = yv * sz;
    v[jj] = val;
    ss = fmaf(val, val, ss);
  }
#pragma unroll
  for (int off = 32; off > 0; off >>= 1) ss += __shfl_xor(ss, off, 64);
  __shared__ float red[4];
  if ((tid & 63) == 0) red[tid >> 6] = ss;
  __syncthreads();
  float tot = red[0] + red[1] + red[2] + red[3];
  float rs = rsqrtf(tot * (1.f / 1536.f) + 1e-5f);
#pragma unroll
  for (int jj = 0; jj < 6; ++jj) {
    int c = jj * 256 + tid;
    zr[c] = (_Float16)(v[jj] * rs * nw[c]);
  }
}

// ---------------------------------------------------------------------------
extern "C" void kernel_launch(void* const* d_in, const int* in_sizes, int n_in,
                              void* d_out, int out_size, void* d_ws, size_t ws_size,
                              hipStream_t stream)
{
  const float* x_in = (const float*)d_in[0];
  const int*   tids = (const int*)d_in[1];
  const float* ipw  = (const float*)d_in[2];
  const float* cw   = (const float*)d_in[3];
  const float* cb   = (const float*)d_in[4];
  const float* dtb  = (const float*)d_in[5];
  const float* alog = (const float*)d_in[6];
  const float* Dv   = (const float*)d_in[7];
  const float* nw   = (const float*)d_in[8];
  const float* opw  = (const float*)d_in[9];
  const float* hw   = (const float*)d_in[10];
  const float* hb   = (const float*)d_in[11];
  const float* how  = (const float*)d_in[12];
  const float* hob  = (const float*)d_in[13];
  float* out = (float*)d_out;

  char* p = (char*)d_ws;
  _Float16* ipw_b = (_Float16*)p; p += (size_t)14413824 * 2;
  _Float16* opw_b = (_Float16*)p; p += (size_t)7077888 * 2;
  _Float16* hw_b  = (_Float16*)p; p += (size_t)1179648 * 2;
  _Float16* how_b = (_Float16*)p; p += (size_t)786432 * 2;
  float*    hob_p = (float*)p;    p += (size_t)1024 * 4;
  const size_t used_w = (size_t)(p - (char*)d_ws);
  const size_t PB = 54528000;
  int nb = 4;
  while (nb > 1 && used_w + (size_t)nb * PB > ws_size) nb >>= 1;

  cvt_kernel<<<8192, 256, 0, stream>>>(ipw, ipw_b, 14413824 / 4);
  cvt_kernel<<<6912, 256, 0, stream>>>(opw, opw_b, 7077888 / 4);
  cvt_kernel<<<1152, 256, 0, stream>>>(hw, hw_b, 1179648 / 4);
  pack_head_kernel<<<3072, 256, 0, stream>>>(how, hob, how_b, hob_p);

  for (int b0 = 0; b0 < BATCH; b0 += nb) {
    const int MT = nb * L_SEQ;
    _Float16* zx    = (_Float16*)p;
    _Float16* ybuf  = zx + (size_t)MT * ZXP;
    _Float16* bcbuf = ybuf + (size_t)MT * D_INNER;
    float*    Hseg  = (float*)(bcbuf + (size_t)MT * 32);
    float*    cumq  = Hseg + (size_t)nb * NHEADS * NSEG * 1024;
    _Float16* xbuf  = (_Float16*)(cumq + (size_t)MT * NHEADS);
    _Float16* hbuf  = zx;

    cvt_kernel<<<6144, 256, 0, stream>>>(x_in + (size_t)b0 * L_SEQ * DIMM,
                                         xbuf, (long)MT * DIMM / 4);

    for (int i = 0; i < 6; ++i) {
      gemm_mfma<0><<<dim3((D_IPROJ + 127) / 128, MT / 128), 256, 0, stream>>>(
          xbuf, DIMM, ipw_b + (size_t)i * D_IPROJ * DIMM, nullptr,
          zx, ZXP, 0, MT, D_IPROJ, DIMM, nullptr, 0);
      scanA_kernel<<<nb * NHEADS * NSEG, 64, 0, stream>>>(
          zx, cw + (size_t)i * CONVD * 4, cb + i * CONVD,
          dtb + i * NHEADS, alog + i * NHEADS, Dv + i * NHEADS,
          ybuf, bcbuf, Hseg, cumq);
      scanB_kernel<<<nb * NHEADS, 1024, 0, stream>>>(Hseg, cumq);
      scanC_kernel<<<nb * NHEADS * NSEG, 64, 0, stream>>>(ybuf, bcbuf, Hseg, cumq);
      norm_kernel<<<MT, 256, 0, stream>>>(ybuf, zx, nw + i * D_INNER);
      gemm_mfma<0><<<dim3(DIMM / 128, MT / 128), 256, 0, stream>>>(
          zx, ZXP, opw_b + (size_t)i * DIMM * D_INNER, nullptr,
          xbuf, DIMM, 0, MT, DIMM, D_INNER, nullptr, 0);
    }

    for (int t = 0; t < 2; ++t) {
      gemm_mfma<2><<<dim3(DIMM / 128, MT / 128), 256, 0, stream>>>(
          xbuf, DIMM, hw_b + (size_t)t * DIMM * DIMM, hb + t * DIMM,
          hbuf, DIMM, 0, MT, DIMM, DIMM, nullptr, 0);
      gemm_mfma<3><<<dim3(4, MT / 128), 256, 0, stream>>>(
          hbuf, DIMM, how_b + (size_t)t * 512 * DIMM, hob_p + t * 512,
          out + (size_t)t * 4 * 16384 * 128 + (size_t)b0 * L_SEQ * 128,
          128, (long)16384 * 128, MT, 512, DIMM,
          tids + (size_t)b0 * L_SEQ, t);
    }
  }
}